// Round 1
// baseline (3349.165 us; speedup 1.0000x reference)
//
#include <hip/hip_runtime.h>
#include <math.h>

#define HID    2048
#define NH     16
#define HD     128
#define SEQ    2048
#define NBATCH 2

// ---------------------------------------------------------------------------
// RoPE tables: cos/sin[s][i], i in [0,64), freq = s / 10000^(i/64)
// ---------------------------------------------------------------------------
__global__ __launch_bounds__(256) void rope_table_kernel(float* __restrict__ ct,
                                                         float* __restrict__ st) {
    int idx = blockIdx.x * 256 + threadIdx.x;
    if (idx >= SEQ * 64) return;
    int s = idx >> 6;
    int i = idx & 63;
    double inv = pow(10000.0, -(double)i / 64.0);
    float freq = (float)s * (float)inv;
    ct[idx] = cosf(freq);
    st[idx] = sinf(freq);
}

// ---------------------------------------------------------------------------
// fp32 GEMM: C[m][n] = sum_k A[m][k] * B[n][k] + bias[n]
// Tile 128x128, BK=8, 256 threads, 8x8 micro-tile per thread.
// MODE 0: QKV — epilogue applies RoPE to q,k and scatters to [b][h][s][d]
// MODE 1: out-proj — plain row-major store to C
// ---------------------------------------------------------------------------
template <int MODE>
__global__ __launch_bounds__(256) void gemm_kernel(
    const float* __restrict__ A, const float* __restrict__ Bm,
    const float* __restrict__ bias, float* __restrict__ C,
    float* __restrict__ qb, float* __restrict__ kb, float* __restrict__ vb,
    const float* __restrict__ ct, const float* __restrict__ st, int K) {
    __shared__ float As[8][128];
    __shared__ float Bs[8][128];

    const int t  = threadIdx.x;
    const int tx = t & 15;
    const int ty = t >> 4;
    const int m0 = blockIdx.y * 128;
    const int n0 = blockIdx.x * 128;
    const int lr = t >> 1;         // 0..127
    const int lc = (t & 1) * 4;    // 0 or 4

    const float* Ap = A  + (size_t)(m0 + lr) * K + lc;
    const float* Bp = Bm + (size_t)(n0 + lr) * K + lc;

    float acc[8][8];
#pragma unroll
    for (int i = 0; i < 8; ++i)
#pragma unroll
        for (int j = 0; j < 8; ++j) acc[i][j] = 0.0f;

    for (int kt = 0; kt < K; kt += 8) {
        float4 a4 = *(const float4*)(Ap + kt);
        float4 b4 = *(const float4*)(Bp + kt);
        __syncthreads();  // previous compute done before overwrite
        As[lc + 0][lr] = a4.x; As[lc + 1][lr] = a4.y;
        As[lc + 2][lr] = a4.z; As[lc + 3][lr] = a4.w;
        Bs[lc + 0][lr] = b4.x; Bs[lc + 1][lr] = b4.y;
        Bs[lc + 2][lr] = b4.z; Bs[lc + 3][lr] = b4.w;
        __syncthreads();
#pragma unroll
        for (int k = 0; k < 8; ++k) {
            float av[8], bv[8];
            *(float4*)&av[0] = *(const float4*)&As[k][ty * 8];
            *(float4*)&av[4] = *(const float4*)&As[k][ty * 8 + 4];
            *(float4*)&bv[0] = *(const float4*)&Bs[k][tx * 8];
            *(float4*)&bv[4] = *(const float4*)&Bs[k][tx * 8 + 4];
#pragma unroll
            for (int i = 0; i < 8; ++i)
#pragma unroll
                for (int j = 0; j < 8; ++j)
                    acc[i][j] = fmaf(av[i], bv[j], acc[i][j]);
        }
    }

    float bcol[8];
#pragma unroll
    for (int j = 0; j < 8; ++j) bcol[j] = bias[n0 + tx * 8 + j];

    if (MODE == 0) {
        const int which = n0 >> 11;            // 0=q 1=k 2=v (tile of 128 cols = 1 head)
        const int h     = (n0 & 2047) >> 7;
        float* dst = (which == 0) ? qb : ((which == 1) ? kb : vb);
#pragma unroll
        for (int i = 0; i < 8; ++i) {
            int m  = m0 + ty * 8 + i;
            int bb = m >> 11;
            int s  = m & 2047;
            float v[8];
#pragma unroll
            for (int j = 0; j < 8; ++j) v[j] = acc[i][j] + bcol[j];
            if (which < 2) {
#pragma unroll
                for (int p = 0; p < 4; ++p) {
                    int   fi = tx * 4 + p;           // pair index d/2
                    float c  = ct[s * 64 + fi];
                    float sn = st[s * 64 + fi];
                    float e = v[2 * p], o = v[2 * p + 1];
                    v[2 * p]     = e * c - o * sn;
                    v[2 * p + 1] = e * sn + o * c;
                }
            }
            float* drow = dst + ((size_t)(bb * NH + h) * SEQ + s) * HD + tx * 8;
            *(float4*)drow       = make_float4(v[0], v[1], v[2], v[3]);
            *(float4*)(drow + 4) = make_float4(v[4], v[5], v[6], v[7]);
        }
    } else {
#pragma unroll
        for (int i = 0; i < 8; ++i) {
            int m = m0 + ty * 8 + i;
            float* crow = C + (size_t)m * HID + n0 + tx * 8;
            *(float4*)crow =
                make_float4(acc[i][0] + bcol[0], acc[i][1] + bcol[1],
                            acc[i][2] + bcol[2], acc[i][3] + bcol[3]);
            *(float4*)(crow + 4) =
                make_float4(acc[i][4] + bcol[4], acc[i][5] + bcol[5],
                            acc[i][6] + bcol[6], acc[i][7] + bcol[7]);
        }
    }
}

// ---------------------------------------------------------------------------
// Flash attention, fp32. Block = (b, h, q-tile of 64). BK = 32.
// Thread map (both phases share ty -> q-rows 4*ty..4*ty+3):
//   scores: kj = 2*tx + {0,1};  PV: d = 8*tx + {0..7}
// ---------------------------------------------------------------------------
__global__ __launch_bounds__(256) void attn_kernel(
    const float* __restrict__ qb, const float* __restrict__ kb,
    const float* __restrict__ vb, const float* __restrict__ mask,
    float* __restrict__ ctx) {
    __shared__ float Qs[64][132];
    __shared__ float KVs[32][132];
    __shared__ float Ps[64][33];

    const int t  = threadIdx.x;
    const int tx = t & 15;
    const int ty = t >> 4;
    const int q0 = blockIdx.x * 64;
    const int h  = blockIdx.y;
    const int bb = blockIdx.z;

    const size_t bh = (size_t)(bb * NH + h) * SEQ * HD;
    const float* qbase = qb + bh;
    const float* kbase = kb + bh;
    const float* vbase = vb + bh;
    const float* mrow  = mask + (size_t)bb * SEQ;

    // stage Q tile (64 x 128)
    {
        int r0 = t >> 5;
        int cc = (t & 31) * 4;
#pragma unroll
        for (int u = 0; u < 8; ++u) {
            int r = r0 + 8 * u;
            *(float4*)&Qs[r][cc] =
                *(const float4*)(qbase + (size_t)(q0 + r) * HD + cc);
        }
    }

    const float scale = 0.08838834764831845f;  // 1/sqrt(128)
    float m_i[4], l_i[4], acc[4][8];
#pragma unroll
    for (int i = 0; i < 4; ++i) {
        m_i[i] = -INFINITY;
        l_i[i] = 0.0f;
#pragma unroll
        for (int j = 0; j < 8; ++j) acc[i][j] = 0.0f;
    }

    const int r0 = t >> 5;
    const int cc = (t & 31) * 4;

    for (int kt = 0; kt < SEQ / 32; ++kt) {
        // load K tile into regs
        float4 kreg[4];
#pragma unroll
        for (int u = 0; u < 4; ++u)
            kreg[u] = *(const float4*)(kbase + (size_t)(kt * 32 + r0 + 8 * u) * HD + cc);
        __syncthreads();  // prev PV done with KVs/Ps
#pragma unroll
        for (int u = 0; u < 4; ++u) *(float4*)&KVs[r0 + 8 * u][cc] = kreg[u];
        __syncthreads();  // K visible (also covers Q staging on first iter)

        // prefetch V tile into regs (overlaps with score compute)
        float4 vreg[4];
#pragma unroll
        for (int u = 0; u < 4; ++u)
            vreg[u] = *(const float4*)(vbase + (size_t)(kt * 32 + r0 + 8 * u) * HD + cc);

        // scores: 4 q-rows x 2 k-cols per thread
        float sc[4][2];
#pragma unroll
        for (int i = 0; i < 4; ++i) { sc[i][0] = 0.0f; sc[i][1] = 0.0f; }
#pragma unroll 8
        for (int d = 0; d < HD; d += 4) {
            float4 k0 = *(const float4*)&KVs[2 * tx][d];
            float4 k1 = *(const float4*)&KVs[2 * tx + 1][d];
#pragma unroll
            for (int i = 0; i < 4; ++i) {
                float4 q = *(const float4*)&Qs[4 * ty + i][d];
                sc[i][0] += q.x * k0.x + q.y * k0.y + q.z * k0.z + q.w * k0.w;
                sc[i][1] += q.x * k1.x + q.y * k1.y + q.z * k1.z + q.w * k1.w;
            }
        }

        float mk0 = mrow[kt * 32 + 2 * tx];
        float mk1 = mrow[kt * 32 + 2 * tx + 1];
        float alpha[4];
#pragma unroll
        for (int i = 0; i < 4; ++i) {
            float s0 = sc[i][0] * scale + mk0;
            float s1 = sc[i][1] * scale + mk1;
            float rm = fmaxf(s0, s1);
#pragma unroll
            for (int off = 1; off < 16; off <<= 1)
                rm = fmaxf(rm, __shfl_xor(rm, off));
            float mnew = fmaxf(m_i[i], rm);
            alpha[i] = __expf(m_i[i] - mnew);
            float p0 = __expf(s0 - mnew);
            float p1 = __expf(s1 - mnew);
            float ts = p0 + p1;
#pragma unroll
            for (int off = 1; off < 16; off <<= 1) ts += __shfl_xor(ts, off);
            l_i[i] = l_i[i] * alpha[i] + ts;
            m_i[i] = mnew;
            Ps[4 * ty + i][2 * tx]     = p0;
            Ps[4 * ty + i][2 * tx + 1] = p1;
        }

        __syncthreads();  // K reads + Ps writes done
#pragma unroll
        for (int u = 0; u < 4; ++u) *(float4*)&KVs[r0 + 8 * u][cc] = vreg[u];
        __syncthreads();  // V + Ps visible

        // PV: rescale then accumulate
#pragma unroll
        for (int i = 0; i < 4; ++i)
#pragma unroll
            for (int j = 0; j < 8; ++j) acc[i][j] *= alpha[i];
#pragma unroll 4
        for (int kj = 0; kj < 32; ++kj) {
            float4 v0 = *(const float4*)&KVs[kj][8 * tx];
            float4 v1 = *(const float4*)&KVs[kj][8 * tx + 4];
#pragma unroll
            for (int i = 0; i < 4; ++i) {
                float pp = Ps[4 * ty + i][kj];
                acc[i][0] = fmaf(pp, v0.x, acc[i][0]);
                acc[i][1] = fmaf(pp, v0.y, acc[i][1]);
                acc[i][2] = fmaf(pp, v0.z, acc[i][2]);
                acc[i][3] = fmaf(pp, v0.w, acc[i][3]);
                acc[i][4] = fmaf(pp, v1.x, acc[i][4]);
                acc[i][5] = fmaf(pp, v1.y, acc[i][5]);
                acc[i][6] = fmaf(pp, v1.z, acc[i][6]);
                acc[i][7] = fmaf(pp, v1.w, acc[i][7]);
            }
        }
    }

    // epilogue: ctx[b][s][h*128 + d]
#pragma unroll
    for (int i = 0; i < 4; ++i) {
        float inv = 1.0f / l_i[i];
        int s = q0 + 4 * ty + i;
        float* crow = ctx + (size_t)(bb * SEQ + s) * HID + h * HD + 8 * tx;
        *(float4*)crow = make_float4(acc[i][0] * inv, acc[i][1] * inv,
                                     acc[i][2] * inv, acc[i][3] * inv);
        *(float4*)(crow + 4) = make_float4(acc[i][4] * inv, acc[i][5] * inv,
                                           acc[i][6] * inv, acc[i][7] * inv);
    }
}

// ---------------------------------------------------------------------------
extern "C" void kernel_launch(void* const* d_in, const int* in_sizes, int n_in,
                              void* d_out, int out_size, void* d_ws, size_t ws_size,
                              hipStream_t stream) {
    const float* hs   = (const float*)d_in[0];
    const float* mask = (const float*)d_in[1];
    const float* Wqkv = (const float*)d_in[2];
    const float* bqkv = (const float*)d_in[3];
    const float* Wout = (const float*)d_in[4];
    const float* bout = (const float*)d_in[5];
    float* out = (float*)d_out;

    float* ws    = (float*)d_ws;
    float* cos_t = ws;
    float* sin_t = cos_t + SEQ * 64;
    const size_t qkv_elems = (size_t)NBATCH * NH * SEQ * HD;  // 8.39M floats
    float* qb  = sin_t + SEQ * 64;
    float* kb  = qb + qkv_elems;
    float* vb  = kb + qkv_elems;
    float* ctx = vb + qkv_elems;

    rope_table_kernel<<<(SEQ * 64 + 255) / 256, 256, 0, stream>>>(cos_t, sin_t);

    // QKV: M=4096 (b*s), N=6144, K=2048
    gemm_kernel<0><<<dim3(48, 32), 256, 0, stream>>>(
        hs, Wqkv, bqkv, nullptr, qb, kb, vb, cos_t, sin_t, HID);

    // attention: (q-tile, head, batch)
    attn_kernel<<<dim3(SEQ / 64, NH, NBATCH), 256, 0, stream>>>(
        qb, kb, vb, mask, ctx);

    // out-proj: M=4096, N=2048, K=2048
    gemm_kernel<1><<<dim3(16, 32), 256, 0, stream>>>(
        ctx, Wout, bout, out, nullptr, nullptr, nullptr, nullptr, nullptr, HID);
}

// Round 3
// 3142.499 us; speedup vs baseline: 1.0658x; 1.0658x over previous
//
#include <hip/hip_runtime.h>
#include <math.h>

#define HID    2048
#define NH     16
#define HD     128
#define SEQ    2048
#define NBATCH 2

// ---------------------------------------------------------------------------
// RoPE tables: cos/sin[s][i], i in [0,64), freq = s / 10000^(i/64)
// ---------------------------------------------------------------------------
__global__ __launch_bounds__(256) void rope_table_kernel(float* __restrict__ ct,
                                                         float* __restrict__ st) {
    int idx = blockIdx.x * 256 + threadIdx.x;
    if (idx >= SEQ * 64) return;
    int s = idx >> 6;
    int i = idx & 63;
    double inv = pow(10000.0, -(double)i / 64.0);
    float freq = (float)s * (float)inv;
    ct[idx] = cosf(freq);
    st[idx] = sinf(freq);
}

// ---------------------------------------------------------------------------
// fp32 GEMM: C[m][n] = sum_k A[m][k] * B[n][k] + bias[n]
// Tile 128x128, BK=8, 256 threads, 8x8 micro-tile per thread.
// MODE 0: QKV — epilogue applies RoPE to q,k and scatters to [b][h][s][d]
// MODE 1: out-proj — plain row-major store to C
// ---------------------------------------------------------------------------
template <int MODE>
__global__ __launch_bounds__(256) void gemm_kernel(
    const float* __restrict__ A, const float* __restrict__ Bm,
    const float* __restrict__ bias, float* __restrict__ C,
    float* __restrict__ qb, float* __restrict__ kb, float* __restrict__ vb,
    const float* __restrict__ ct, const float* __restrict__ st, int K) {
    __shared__ float As[8][128];
    __shared__ float Bs[8][128];

    const int t  = threadIdx.x;
    const int tx = t & 15;
    const int ty = t >> 4;
    const int m0 = blockIdx.y * 128;
    const int n0 = blockIdx.x * 128;
    const int lr = t >> 1;         // 0..127
    const int lc = (t & 1) * 4;    // 0 or 4

    const float* Ap = A  + (size_t)(m0 + lr) * K + lc;
    const float* Bp = Bm + (size_t)(n0 + lr) * K + lc;

    float acc[8][8];
#pragma unroll
    for (int i = 0; i < 8; ++i)
#pragma unroll
        for (int j = 0; j < 8; ++j) acc[i][j] = 0.0f;

    for (int kt = 0; kt < K; kt += 8) {
        float4 a4 = *(const float4*)(Ap + kt);
        float4 b4 = *(const float4*)(Bp + kt);
        __syncthreads();  // previous compute done before overwrite
        As[lc + 0][lr] = a4.x; As[lc + 1][lr] = a4.y;
        As[lc + 2][lr] = a4.z; As[lc + 3][lr] = a4.w;
        Bs[lc + 0][lr] = b4.x; Bs[lc + 1][lr] = b4.y;
        Bs[lc + 2][lr] = b4.z; Bs[lc + 3][lr] = b4.w;
        __syncthreads();
#pragma unroll
        for (int k = 0; k < 8; ++k) {
            float av[8], bv[8];
            *(float4*)&av[0] = *(const float4*)&As[k][ty * 8];
            *(float4*)&av[4] = *(const float4*)&As[k][ty * 8 + 4];
            *(float4*)&bv[0] = *(const float4*)&Bs[k][tx * 8];
            *(float4*)&bv[4] = *(const float4*)&Bs[k][tx * 8 + 4];
#pragma unroll
            for (int i = 0; i < 8; ++i)
#pragma unroll
                for (int j = 0; j < 8; ++j)
                    acc[i][j] = fmaf(av[i], bv[j], acc[i][j]);
        }
    }

    float bcol[8];
#pragma unroll
    for (int j = 0; j < 8; ++j) bcol[j] = bias[n0 + tx * 8 + j];

    if (MODE == 0) {
        const int which = n0 >> 11;            // 0=q 1=k 2=v (tile of 128 cols = 1 head)
        const int h     = (n0 & 2047) >> 7;
        float* dst = (which == 0) ? qb : ((which == 1) ? kb : vb);
#pragma unroll
        for (int i = 0; i < 8; ++i) {
            int m  = m0 + ty * 8 + i;
            int bb = m >> 11;
            int s  = m & 2047;
            float v[8];
#pragma unroll
            for (int j = 0; j < 8; ++j) v[j] = acc[i][j] + bcol[j];
            if (which < 2) {
#pragma unroll
                for (int p = 0; p < 4; ++p) {
                    int   fi = tx * 4 + p;           // pair index d/2
                    float c  = ct[s * 64 + fi];
                    float sn = st[s * 64 + fi];
                    float e = v[2 * p], o = v[2 * p + 1];
                    v[2 * p]     = e * c - o * sn;
                    v[2 * p + 1] = e * sn + o * c;
                }
            }
            float* drow = dst + ((size_t)(bb * NH + h) * SEQ + s) * HD + tx * 8;
            *(float4*)drow       = make_float4(v[0], v[1], v[2], v[3]);
            *(float4*)(drow + 4) = make_float4(v[4], v[5], v[6], v[7]);
        }
    } else {
#pragma unroll
        for (int i = 0; i < 8; ++i) {
            int m = m0 + ty * 8 + i;
            float* crow = C + (size_t)m * HID + n0 + tx * 8;
            *(float4*)crow =
                make_float4(acc[i][0] + bcol[0], acc[i][1] + bcol[1],
                            acc[i][2] + bcol[2], acc[i][3] + bcol[3]);
            *(float4*)(crow + 4) =
                make_float4(acc[i][4] + bcol[4], acc[i][5] + bcol[5],
                            acc[i][6] + bcol[6], acc[i][7] + bcol[7]);
        }
    }
}

// ---------------------------------------------------------------------------
// Flash attention, fp32. Block = (b, h, q-tile of 64). BK = 32.
// R1-proven barrier/Ps structure; only the lane->address maps changed:
//   scores: kj = tx, tx+16      (K reads: banks 4tx+d -> 2-way, free)
//   PV:     d  = 4tx+{0..3}, 64+4tx+{0..3}   (V reads 2-way, free)
//   Ps cols tx, tx+16 (row stride 33 keeps PV reads conflict-free)
// ---------------------------------------------------------------------------
__global__ __launch_bounds__(256) void attn_kernel(
    const float* __restrict__ qb, const float* __restrict__ kb,
    const float* __restrict__ vb, const float* __restrict__ mask,
    float* __restrict__ ctx) {
    __shared__ float Qs[64][132];
    __shared__ float KVs[32][132];
    __shared__ float Ps[64][33];

    const int t  = threadIdx.x;
    const int tx = t & 15;
    const int ty = t >> 4;          // 0..15, q-rows 4*ty..4*ty+3
    const int q0 = blockIdx.x * 64;
    const int h  = blockIdx.y;
    const int bb = blockIdx.z;

    const size_t bh = (size_t)(bb * NH + h) * SEQ * HD;
    const float* qbase = qb + bh;
    const float* kbase = kb + bh;
    const float* vbase = vb + bh;
    const float* mrow  = mask + (size_t)bb * SEQ;

    const int r0 = t >> 5;          // 0..7
    const int cc = (t & 31) * 4;    // 0..124

    // stage Q tile (64 x 128)
#pragma unroll
    for (int u = 0; u < 8; ++u) {
        int r = r0 + 8 * u;
        *(float4*)&Qs[r][cc] =
            *(const float4*)(qbase + (size_t)(q0 + r) * HD + cc);
    }

    const float scale = 0.08838834764831845f;  // 1/sqrt(128)
    float m_i[4], l_i[4], acc[4][8];
#pragma unroll
    for (int i = 0; i < 4; ++i) {
        m_i[i] = -INFINITY;
        l_i[i] = 0.0f;
#pragma unroll
        for (int j = 0; j < 8; ++j) acc[i][j] = 0.0f;
    }

    for (int kt = 0; kt < SEQ / 32; ++kt) {
        // load K tile into regs
        float4 kreg[4];
#pragma unroll
        for (int u = 0; u < 4; ++u)
            kreg[u] = *(const float4*)(kbase + (size_t)(kt * 32 + r0 + 8 * u) * HD + cc);
        __syncthreads();  // prev PV done with KVs/Ps (covers Q staging on iter 0)
#pragma unroll
        for (int u = 0; u < 4; ++u) *(float4*)&KVs[r0 + 8 * u][cc] = kreg[u];
        __syncthreads();  // K visible

        // prefetch V tile into regs (overlaps score compute)
        float4 vreg[4];
#pragma unroll
        for (int u = 0; u < 4; ++u)
            vreg[u] = *(const float4*)(vbase + (size_t)(kt * 32 + r0 + 8 * u) * HD + cc);

        // scores: 4 q-rows x 2 k-cols (kj = tx, tx+16) per thread
        float sc[4][2];
#pragma unroll
        for (int i = 0; i < 4; ++i) { sc[i][0] = 0.0f; sc[i][1] = 0.0f; }
#pragma unroll 8
        for (int d = 0; d < HD; d += 4) {
            float4 k0 = *(const float4*)&KVs[tx][d];
            float4 k1 = *(const float4*)&KVs[tx + 16][d];
#pragma unroll
            for (int i = 0; i < 4; ++i) {
                float4 q = *(const float4*)&Qs[4 * ty + i][d];
                sc[i][0] += q.x * k0.x + q.y * k0.y + q.z * k0.z + q.w * k0.w;
                sc[i][1] += q.x * k1.x + q.y * k1.y + q.z * k1.z + q.w * k1.w;
            }
        }

        float mk0 = mrow[kt * 32 + tx];
        float mk1 = mrow[kt * 32 + tx + 16];
        float alpha[4];
#pragma unroll
        for (int i = 0; i < 4; ++i) {
            float s0 = sc[i][0] * scale + mk0;
            float s1 = sc[i][1] * scale + mk1;
            float rm = fmaxf(s0, s1);
#pragma unroll
            for (int off = 1; off < 16; off <<= 1)
                rm = fmaxf(rm, __shfl_xor(rm, off));
            float mnew = fmaxf(m_i[i], rm);
            alpha[i] = __expf(m_i[i] - mnew);
            float p0 = __expf(s0 - mnew);
            float p1 = __expf(s1 - mnew);
            float ts = p0 + p1;
#pragma unroll
            for (int off = 1; off < 16; off <<= 1) ts += __shfl_xor(ts, off);
            l_i[i] = l_i[i] * alpha[i] + ts;
            m_i[i] = mnew;
            Ps[4 * ty + i][tx]      = p0;
            Ps[4 * ty + i][tx + 16] = p1;
        }

        __syncthreads();  // K reads + Ps writes done
#pragma unroll
        for (int u = 0; u < 4; ++u) *(float4*)&KVs[r0 + 8 * u][cc] = vreg[u];
        __syncthreads();  // V + Ps visible

        // PV: rescale then accumulate
#pragma unroll
        for (int i = 0; i < 4; ++i)
#pragma unroll
            for (int j = 0; j < 8; ++j) acc[i][j] *= alpha[i];
#pragma unroll 4
        for (int kj = 0; kj < 32; ++kj) {
            float4 v0 = *(const float4*)&KVs[kj][4 * tx];
            float4 v1 = *(const float4*)&KVs[kj][64 + 4 * tx];
#pragma unroll
            for (int i = 0; i < 4; ++i) {
                float pp = Ps[4 * ty + i][kj];
                acc[i][0] = fmaf(pp, v0.x, acc[i][0]);
                acc[i][1] = fmaf(pp, v0.y, acc[i][1]);
                acc[i][2] = fmaf(pp, v0.z, acc[i][2]);
                acc[i][3] = fmaf(pp, v0.w, acc[i][3]);
                acc[i][4] = fmaf(pp, v1.x, acc[i][4]);
                acc[i][5] = fmaf(pp, v1.y, acc[i][5]);
                acc[i][6] = fmaf(pp, v1.z, acc[i][6]);
                acc[i][7] = fmaf(pp, v1.w, acc[i][7]);
            }
        }
    }

    // epilogue: ctx[b][s][h*128 + d], d = 4*tx+{0..3} and 64+4*tx+{0..3}
#pragma unroll
    for (int i = 0; i < 4; ++i) {
        float inv = 1.0f / l_i[i];
        int s = q0 + 4 * ty + i;
        float* crow = ctx + (size_t)(bb * SEQ + s) * HID + h * HD;
        *(float4*)(crow + 4 * tx) =
            make_float4(acc[i][0] * inv, acc[i][1] * inv,
                        acc[i][2] * inv, acc[i][3] * inv);
        *(float4*)(crow + 64 + 4 * tx) =
            make_float4(acc[i][4] * inv, acc[i][5] * inv,
                        acc[i][6] * inv, acc[i][7] * inv);
    }
}

// ---------------------------------------------------------------------------
extern "C" void kernel_launch(void* const* d_in, const int* in_sizes, int n_in,
                              void* d_out, int out_size, void* d_ws, size_t ws_size,
                              hipStream_t stream) {
    const float* hs   = (const float*)d_in[0];
    const float* mask = (const float*)d_in[1];
    const float* Wqkv = (const float*)d_in[2];
    const float* bqkv = (const float*)d_in[3];
    const float* Wout = (const float*)d_in[4];
    const float* bout = (const float*)d_in[5];
    float* out = (float*)d_out;

    float* ws    = (float*)d_ws;
    float* cos_t = ws;
    float* sin_t = cos_t + SEQ * 64;
    const size_t qkv_elems = (size_t)NBATCH * NH * SEQ * HD;  // 8.39M floats
    float* qb  = sin_t + SEQ * 64;
    float* kb  = qb + qkv_elems;
    float* vb  = kb + qkv_elems;
    float* ctx = vb + qkv_elems;

    rope_table_kernel<<<(SEQ * 64 + 255) / 256, 256, 0, stream>>>(cos_t, sin_t);

    // QKV: M=4096 (b*s), N=6144, K=2048
    gemm_kernel<0><<<dim3(48, 32), 256, 0, stream>>>(
        hs, Wqkv, bqkv, nullptr, qb, kb, vb, cos_t, sin_t, HID);

    // attention: (q-tile, head, batch)
    attn_kernel<<<dim3(SEQ / 64, NH, NBATCH), 256, 0, stream>>>(
        qb, kb, vb, mask, ctx);

    // out-proj: M=4096, N=2048, K=2048
    gemm_kernel<1><<<dim3(16, 32), 256, 0, stream>>>(
        ctx, Wout, bout, out, nullptr, nullptr, nullptr, nullptr, nullptr, HID);
}

// Round 4
// 2253.822 us; speedup vs baseline: 1.4860x; 1.3943x over previous
//
#include <hip/hip_runtime.h>
#include <math.h>

#define HID    2048
#define NH     16
#define HD     128
#define SEQ    2048
#define NBATCH 2

typedef __attribute__((ext_vector_type(8))) short bf16x8;   // 8 bf16 = 4 VGPRs
typedef __attribute__((ext_vector_type(4))) float f32x4;    // MFMA accumulator

__device__ __forceinline__ short f2bf(float f) {            // fp32 -> bf16 RNE
    union { float f; unsigned u; } x; x.f = f;
    unsigned r = x.u + 0x7fffu + ((x.u >> 16) & 1u);
    return (short)(r >> 16);
}
__device__ __forceinline__ float bf2f(short s) {
    union { unsigned u; float f; } y;
    y.u = ((unsigned)(unsigned short)s) << 16;
    return y.f;
}

// ---------------------------------------------------------------------------
// RoPE tables: cos/sin[s][i], i in [0,64), freq = s / 10000^(i/64)
// ---------------------------------------------------------------------------
__global__ __launch_bounds__(256) void rope_table_kernel(float* __restrict__ ct,
                                                         float* __restrict__ st) {
    int idx = blockIdx.x * 256 + threadIdx.x;
    if (idx >= SEQ * 64) return;
    int s = idx >> 6;
    int i = idx & 63;
    double inv = pow(10000.0, -(double)i / 64.0);
    float freq = (float)s * (float)inv;
    ct[idx] = cosf(freq);
    st[idx] = sinf(freq);
}

// ---------------------------------------------------------------------------
// fp32 GEMM: C[m][n] = sum_k A[m][k] * B[n][k] + bias[n]
// Tile 128x128, BK=8, 256 threads, 8x8 micro-tile per thread.
// MODE 0: QKV — epilogue applies RoPE to q,k; writes q_hi/q_lo/k bf16 [b][h][s][d]
//              and V transposed bf16 [b][h][d][s]
// MODE 1: out-proj — plain fp32 row-major store to C
// ---------------------------------------------------------------------------
template <int MODE>
__global__ __launch_bounds__(256) void gemm_kernel(
    const float* __restrict__ A, const float* __restrict__ Bm,
    const float* __restrict__ bias, float* __restrict__ C,
    short* __restrict__ qhi, short* __restrict__ qlo,
    short* __restrict__ kbf, short* __restrict__ vTt,
    const float* __restrict__ ct, const float* __restrict__ st, int K) {
    __shared__ float As[8][128];
    __shared__ float Bs[8][128];

    const int t  = threadIdx.x;
    const int tx = t & 15;
    const int ty = t >> 4;
    const int m0 = blockIdx.y * 128;
    const int n0 = blockIdx.x * 128;
    const int lr = t >> 1;         // 0..127
    const int lc = (t & 1) * 4;    // 0 or 4

    const float* Ap = A  + (size_t)(m0 + lr) * K + lc;
    const float* Bp = Bm + (size_t)(n0 + lr) * K + lc;

    float acc[8][8];
#pragma unroll
    for (int i = 0; i < 8; ++i)
#pragma unroll
        for (int j = 0; j < 8; ++j) acc[i][j] = 0.0f;

    for (int kt = 0; kt < K; kt += 8) {
        float4 a4 = *(const float4*)(Ap + kt);
        float4 b4 = *(const float4*)(Bp + kt);
        __syncthreads();
        As[lc + 0][lr] = a4.x; As[lc + 1][lr] = a4.y;
        As[lc + 2][lr] = a4.z; As[lc + 3][lr] = a4.w;
        Bs[lc + 0][lr] = b4.x; Bs[lc + 1][lr] = b4.y;
        Bs[lc + 2][lr] = b4.z; Bs[lc + 3][lr] = b4.w;
        __syncthreads();
#pragma unroll
        for (int k = 0; k < 8; ++k) {
            float av[8], bv[8];
            *(float4*)&av[0] = *(const float4*)&As[k][ty * 8];
            *(float4*)&av[4] = *(const float4*)&As[k][ty * 8 + 4];
            *(float4*)&bv[0] = *(const float4*)&Bs[k][tx * 8];
            *(float4*)&bv[4] = *(const float4*)&Bs[k][tx * 8 + 4];
#pragma unroll
            for (int i = 0; i < 8; ++i)
#pragma unroll
                for (int j = 0; j < 8; ++j)
                    acc[i][j] = fmaf(av[i], bv[j], acc[i][j]);
        }
    }

    float bcol[8];
#pragma unroll
    for (int j = 0; j < 8; ++j) bcol[j] = bias[n0 + tx * 8 + j];

    if (MODE == 0) {
        const int which = n0 >> 11;            // 0=q 1=k 2=v (128-col tile = 1 head)
        const int h     = (n0 & 2047) >> 7;
        const int bidx  = m0 >> 11;            // batch (tile never spans batches)
        const int sbase = (m0 & 2047) + ty * 8;
        if (which < 2) {
#pragma unroll
            for (int i = 0; i < 8; ++i) {
                int s = sbase + i;
                float v[8];
#pragma unroll
                for (int j = 0; j < 8; ++j) v[j] = acc[i][j] + bcol[j];
#pragma unroll
                for (int p = 0; p < 4; ++p) {
                    int   fi = tx * 4 + p;     // pair index d/2
                    float c  = ct[s * 64 + fi];
                    float sn = st[s * 64 + fi];
                    float e = v[2 * p], o = v[2 * p + 1];
                    v[2 * p]     = e * c - o * sn;
                    v[2 * p + 1] = e * sn + o * c;
                }
                size_t rowoff = ((size_t)(bidx * NH + h) * SEQ + s) * HD + tx * 8;
                if (which == 0) {
                    bf16x8 hv, lv;
#pragma unroll
                    for (int j = 0; j < 8; ++j) {
                        hv[j] = f2bf(v[j]);
                        lv[j] = f2bf(v[j] - bf2f(hv[j]));
                    }
                    *(bf16x8*)(qhi + rowoff) = hv;
                    *(bf16x8*)(qlo + rowoff) = lv;
                } else {
                    bf16x8 hv;
#pragma unroll
                    for (int j = 0; j < 8; ++j) hv[j] = f2bf(v[j]);
                    *(bf16x8*)(kbf + rowoff) = hv;
                }
            }
        } else {
            // V: write transposed [b][h][d][s] bf16; thread owns 8 s-rows x 8 d-cols
#pragma unroll
            for (int j = 0; j < 8; ++j) {
                int dv = tx * 8 + j;
                bf16x8 col;
#pragma unroll
                for (int i = 0; i < 8; ++i) col[i] = f2bf(acc[i][j] + bcol[j]);
                *(bf16x8*)(vTt + (((size_t)(bidx * NH + h) * HD + dv) * SEQ + sbase)) = col;
            }
        }
    } else {
#pragma unroll
        for (int i = 0; i < 8; ++i) {
            int m = m0 + ty * 8 + i;
            float* crow = C + (size_t)m * HID + n0 + tx * 8;
            *(float4*)crow =
                make_float4(acc[i][0] + bcol[0], acc[i][1] + bcol[1],
                            acc[i][2] + bcol[2], acc[i][3] + bcol[3]);
            *(float4*)(crow + 4) =
                make_float4(acc[i][4] + bcol[4], acc[i][5] + bcol[5],
                            acc[i][6] + bcol[6], acc[i][7] + bcol[7]);
        }
    }
}

// ---------------------------------------------------------------------------
// MFMA flash attention. Block = 256 = 4 independent waves (no __syncthreads).
// Wave handles 16 q-rows; KV tile = 64. mfma_f32_16x16x32_bf16.
//   A-frag:  X[m=lane&15][k=quad*8+j]      (8 contiguous bf16 = b128)
//   B-frag:  Y[n=lane&15][k=quad*8+j]  from row-major [n][k] storage
//   C/D:     row = quad*4+reg, col = lane&15
// QK^T: A=Q (hi+lo split), B=K rows (bf16 [s][d]).  PV: A=P (LDS round-trip,
// wave-private), B=V^T rows (bf16 [d][s]).  Frags read directly from global
// (L2-resident); only LDS is the 2.3 KB/wave P buffer.
// ---------------------------------------------------------------------------
__global__ __launch_bounds__(256, 3) void attn_mfma_kernel(
    const short* __restrict__ qhi, const short* __restrict__ qlo,
    const short* __restrict__ kbf, const short* __restrict__ vTt,
    const float* __restrict__ mask, float* __restrict__ ctx) {
    __shared__ __align__(16) short Pw[4][16][72];   // [wave][q-row][kj] bf16, +8 pad

    const int t    = threadIdx.x;
    const int w    = t >> 6;
    const int lane = t & 63;
    const int m    = lane & 15;
    const int quad = lane >> 4;
    const int q0   = blockIdx.x * 64;
    const int bh   = blockIdx.y;         // b*16 + h
    const int b    = bh >> 4;
    const int h    = bh & 15;

    const size_t base = (size_t)bh * SEQ * HD;
    const short* kp = kbf + base;        // [s][d]
    const short* vp = vTt + base;        // [d][s]
    const float* mrow = mask + (size_t)b * SEQ;

    // Q fragments for this wave's 16 rows (row = q0 + w*16 + m), 4 d-chunks
    const int srow = q0 + w * 16 + m;
    bf16x8 qh[4], ql[4];
    {
        const short* qhp = qhi + base + (size_t)srow * HD;
        const short* qlp = qlo + base + (size_t)srow * HD;
#pragma unroll
        for (int c = 0; c < 4; ++c) {
            qh[c] = *(const bf16x8*)(qhp + 32 * c + 8 * quad);
            ql[c] = *(const bf16x8*)(qlp + 32 * c + 8 * quad);
        }
    }

    const float scale = 0.08838834764831845f;  // 1/sqrt(128)
    f32x4 O[8];
    float m_i[4], l_i[4];
#pragma unroll
    for (int c = 0; c < 8; ++c) O[c] = (f32x4){0.f, 0.f, 0.f, 0.f};
#pragma unroll
    for (int r = 0; r < 4; ++r) { m_i[r] = -INFINITY; l_i[r] = 0.f; }

    for (int kt = 0; kt < SEQ / 64; ++kt) {
        const int k0 = kt * 64;

        float mk[4];
#pragma unroll
        for (int c2 = 0; c2 < 4; ++c2) mk[c2] = mrow[k0 + 16 * c2 + m];

        // ---- QK^T: 4 kj-chunks x 4 d-chunks x (hi,lo) ----
        f32x4 S[4];
#pragma unroll
        for (int c2 = 0; c2 < 4; ++c2) {
            f32x4 acc = (f32x4){0.f, 0.f, 0.f, 0.f};
            const short* krow = kp + (size_t)(k0 + 16 * c2 + m) * HD + 8 * quad;
#pragma unroll
            for (int c = 0; c < 4; ++c) {
                bf16x8 kf = *(const bf16x8*)(krow + 32 * c);
                acc = __builtin_amdgcn_mfma_f32_16x16x32_bf16(qh[c], kf, acc, 0, 0, 0);
                acc = __builtin_amdgcn_mfma_f32_16x16x32_bf16(ql[c], kf, acc, 0, 0, 0);
            }
            S[c2] = acc;
        }

        // ---- online softmax (lane holds rows 4*quad+r, cols 16*c2+m) ----
        float alpha[4], p[4][4];
#pragma unroll
        for (int r = 0; r < 4; ++r) {
            float s0 = S[0][r] * scale + mk[0];
            float s1 = S[1][r] * scale + mk[1];
            float s2 = S[2][r] * scale + mk[2];
            float s3 = S[3][r] * scale + mk[3];
            float rm = fmaxf(fmaxf(s0, s1), fmaxf(s2, s3));
#pragma unroll
            for (int off = 1; off < 16; off <<= 1)
                rm = fmaxf(rm, __shfl_xor(rm, off, 64));
            float mn = fmaxf(m_i[r], rm);
            alpha[r] = __expf(m_i[r] - mn);
            p[0][r] = __expf(s0 - mn);
            p[1][r] = __expf(s1 - mn);
            p[2][r] = __expf(s2 - mn);
            p[3][r] = __expf(s3 - mn);
            float ts = (p[0][r] + p[1][r]) + (p[2][r] + p[3][r]);
#pragma unroll
            for (int off = 1; off < 16; off <<= 1)
                ts += __shfl_xor(ts, off, 64);
            l_i[r] = l_i[r] * alpha[r] + ts;
            m_i[r] = mn;
        }

        // ---- P: C-layout -> A-layout via wave-private LDS (no barrier) ----
#pragma unroll
        for (int c2 = 0; c2 < 4; ++c2)
#pragma unroll
            for (int r = 0; r < 4; ++r)
                Pw[w][4 * quad + r][16 * c2 + m] = f2bf(p[c2][r]);

        // ---- rescale O, then PV ----
#pragma unroll
        for (int c = 0; c < 8; ++c)
#pragma unroll
            for (int r = 0; r < 4; ++r) O[c][r] *= alpha[r];

#pragma unroll
        for (int cc = 0; cc < 2; ++cc) {
            bf16x8 pf = *(const bf16x8*)&Pw[w][m][32 * cc + 8 * quad];
#pragma unroll
            for (int c = 0; c < 8; ++c) {
                bf16x8 vf = *(const bf16x8*)(vp + (size_t)(16 * c + m) * SEQ +
                                             k0 + 32 * cc + 8 * quad);
                O[c] = __builtin_amdgcn_mfma_f32_16x16x32_bf16(pf, vf, O[c], 0, 0, 0);
            }
        }
    }

    // ---- epilogue: ctx[b][s][h*128+dv], lane writes rows 4*quad+r ----
#pragma unroll
    for (int r = 0; r < 4; ++r) {
        float inv = 1.0f / l_i[r];
        int s = q0 + w * 16 + 4 * quad + r;
        float* dst = ctx + ((size_t)(b * SEQ + s)) * HID + h * HD;
#pragma unroll
        for (int c = 0; c < 8; ++c) dst[16 * c + m] = O[c][r] * inv;
    }
}

// ---------------------------------------------------------------------------
extern "C" void kernel_launch(void* const* d_in, const int* in_sizes, int n_in,
                              void* d_out, int out_size, void* d_ws, size_t ws_size,
                              hipStream_t stream) {
    const float* hs   = (const float*)d_in[0];
    const float* mask = (const float*)d_in[1];
    const float* Wqkv = (const float*)d_in[2];
    const float* bqkv = (const float*)d_in[3];
    const float* Wout = (const float*)d_in[4];
    const float* bout = (const float*)d_in[5];
    float* out = (float*)d_out;

    const size_t qkv_elems = (size_t)NBATCH * NH * SEQ * HD;  // 8.39M
    char* p = (char*)d_ws;
    float* cos_t = (float*)p; p += (size_t)SEQ * 64 * 4;
    float* sin_t = (float*)p; p += (size_t)SEQ * 64 * 4;
    short* qhi   = (short*)p; p += qkv_elems * 2;
    short* qlo   = (short*)p; p += qkv_elems * 2;
    short* kbf   = (short*)p; p += qkv_elems * 2;
    short* vTt   = (short*)p; p += qkv_elems * 2;
    float* ctx   = (float*)p;

    rope_table_kernel<<<(SEQ * 64 + 255) / 256, 256, 0, stream>>>(cos_t, sin_t);

    // QKV: M=4096 (b*s), N=6144, K=2048; epilogue emits bf16 q_hi/q_lo/k + vT
    gemm_kernel<0><<<dim3(48, 32), 256, 0, stream>>>(
        hs, Wqkv, bqkv, nullptr, qhi, qlo, kbf, vTt, cos_t, sin_t, HID);

    // attention: (q-tile of 64, b*h)
    attn_mfma_kernel<<<dim3(SEQ / 64, NH * NBATCH), 256, 0, stream>>>(
        qhi, qlo, kbf, vTt, mask, ctx);

    // out-proj: M=4096, N=2048, K=2048 (fp32)
    gemm_kernel<1><<<dim3(16, 32), 256, 0, stream>>>(
        ctx, Wout, bout, out, nullptr, nullptr, nullptr, nullptr,
        nullptr, nullptr, HID);
}

// Round 5
// 901.742 us; speedup vs baseline: 3.7141x; 2.4994x over previous
//
#include <hip/hip_runtime.h>
#include <math.h>

#define HID    2048
#define NH     16
#define HD     128
#define SEQ    2048
#define NBATCH 2

typedef __attribute__((ext_vector_type(8))) short bf16x8;   // 8 bf16 = 4 VGPRs
typedef __attribute__((ext_vector_type(4))) float f32x4;    // MFMA accumulator

__device__ __forceinline__ short f2bf(float f) {            // fp32 -> bf16 RNE
    union { float f; unsigned u; } x; x.f = f;
    unsigned r = x.u + 0x7fffu + ((x.u >> 16) & 1u);
    return (short)(r >> 16);
}
__device__ __forceinline__ float bf2f(short s) {
    union { unsigned u; float f; } y;
    y.u = ((unsigned)(unsigned short)s) << 16;
    return y.f;
}

// async global->LDS, 16 B per lane; LDS dest = wave-uniform base + lane*16
__device__ __forceinline__ void gl_lds16(const short* g, short* l) {
    __builtin_amdgcn_global_load_lds(
        (const __attribute__((address_space(1))) unsigned int*)g,
        (__attribute__((address_space(3))) unsigned int*)l, 16, 0, 0);
}

// ---------------------------------------------------------------------------
// RoPE tables
// ---------------------------------------------------------------------------
__global__ __launch_bounds__(256) void rope_table_kernel(float* __restrict__ ct,
                                                         float* __restrict__ st) {
    int idx = blockIdx.x * 256 + threadIdx.x;
    if (idx >= SEQ * 64) return;
    int s = idx >> 6;
    int i = idx & 63;
    double inv = pow(10000.0, -(double)i / 64.0);
    float freq = (float)s * (float)inv;
    ct[idx] = cosf(freq);
    st[idx] = sinf(freq);
}

// ---------------------------------------------------------------------------
// fp32 -> bf16 hi+lo split (A operands) and hi-only (weights)
// ---------------------------------------------------------------------------
__global__ __launch_bounds__(256) void split_hl_kernel(const float* __restrict__ in,
                                                       short* __restrict__ oh,
                                                       short* __restrict__ ol, int n4) {
    int i = blockIdx.x * 256 + threadIdx.x;
    if (i >= n4) return;
    float4 v = ((const float4*)in)[i];
    short4 h, l;
    h.x = f2bf(v.x); l.x = f2bf(v.x - bf2f(h.x));
    h.y = f2bf(v.y); l.y = f2bf(v.y - bf2f(h.y));
    h.z = f2bf(v.z); l.z = f2bf(v.z - bf2f(h.z));
    h.w = f2bf(v.w); l.w = f2bf(v.w - bf2f(h.w));
    *(short4*)(oh + 4 * (size_t)i) = h;
    *(short4*)(ol + 4 * (size_t)i) = l;
}

__global__ __launch_bounds__(256) void split_h_kernel(const float* __restrict__ in,
                                                      short* __restrict__ oh, int n4) {
    int i = blockIdx.x * 256 + threadIdx.x;
    if (i >= n4) return;
    float4 v = ((const float4*)in)[i];
    short4 h;
    h.x = f2bf(v.x); h.y = f2bf(v.y); h.z = f2bf(v.z); h.w = f2bf(v.w);
    *(short4*)(oh + 4 * (size_t)i) = h;
}

// ---------------------------------------------------------------------------
// bf16 MFMA GEMM: C[m][n] = (Ah+Al)[m][:] . Wh[n][:] + bias[n]
// 128x128 tile, BK=32, 256 thr = 4 waves (2x2 of 64x64), 4x4 16x16x32 MFMAs,
// 2 chains (Ah*Wh + Al*Wh). global_load_lds staging, XOR-swizzled granules.
// MODE 0: QKV -> RoPE (shfl partner) -> qhi/qlo/kbf [b][h][s][d] + vT [b][h][d][s]
// MODE 1: out-proj -> fp32 C
// ---------------------------------------------------------------------------
#define LDSA_H 0
#define LDSA_L 4096
#define LDSB_H 8192

template <int MODE>
__global__ __launch_bounds__(256, 2) void gemm_bf16_kernel(
    const short* __restrict__ Ah, const short* __restrict__ Al,
    const short* __restrict__ Bh, const float* __restrict__ bias,
    float* __restrict__ C,
    short* __restrict__ qhi, short* __restrict__ qlo,
    short* __restrict__ kbf, short* __restrict__ vTt,
    const float* __restrict__ ct, const float* __restrict__ st) {
    __shared__ short lds[18432];   // staging 24 KB; epilogue V-transpose 36 KB

    const int t     = threadIdx.x;
    const int w     = t >> 6;
    const int lane  = t & 63;
    const int mfrag = lane & 15;
    const int quad  = lane >> 4;
    const int wm    = (w >> 1) * 64;
    const int wn    = (w & 1) * 64;
    const int m0    = blockIdx.y * 128;
    const int n0    = blockIdx.x * 128;

    // staging source addresses (swizzled granule within each 64 B row-chunk)
    const int srow   = lane >> 2;
    const int schunk = (((lane & 3) ^ ((lane >> 3) & 3))) * 8;
    const short* gA0 = Ah + (size_t)(m0 + w * 16 + srow) * HID + schunk;
    const short* gA1 = Ah + (size_t)(m0 + 64 + w * 16 + srow) * HID + schunk;
    const short* gL0 = Al + (size_t)(m0 + w * 16 + srow) * HID + schunk;
    const short* gL1 = Al + (size_t)(m0 + 64 + w * 16 + srow) * HID + schunk;
    const short* gB0 = Bh + (size_t)(n0 + w * 16 + srow) * HID + schunk;
    const short* gB1 = Bh + (size_t)(n0 + 64 + w * 16 + srow) * HID + schunk;
    short* lA0 = &lds[LDSA_H + (w * 16) * 32];
    short* lA1 = &lds[LDSA_H + (64 + w * 16) * 32];
    short* lL0 = &lds[LDSA_L + (w * 16) * 32];
    short* lL1 = &lds[LDSA_L + (64 + w * 16) * 32];
    short* lB0 = &lds[LDSB_H + (w * 16) * 32];
    short* lB1 = &lds[LDSB_H + (64 + w * 16) * 32];

    // fragment read offsets (inverse swizzle)
    const int chA = 8 * (quad ^ ((mfrag >> 1) & 3));

    f32x4 acc[4][4];
#pragma unroll
    for (int i = 0; i < 4; ++i)
#pragma unroll
        for (int j = 0; j < 4; ++j) acc[i][j] = (f32x4){0.f, 0.f, 0.f, 0.f};

    for (int kt = 0; kt < HID; kt += 32) {
        __syncthreads();   // prior frag reads done before overwrite
        gl_lds16(gA0 + kt, lA0);
        gl_lds16(gA1 + kt, lA1);
        gl_lds16(gL0 + kt, lL0);
        gl_lds16(gL1 + kt, lL1);
        gl_lds16(gB0 + kt, lB0);
        gl_lds16(gB1 + kt, lB1);
        __syncthreads();   // vmcnt drained by compiler before barrier

        bf16x8 ah[4], al[4], bh[4];
#pragma unroll
        for (int mt = 0; mt < 4; ++mt) {
            ah[mt] = *(const bf16x8*)&lds[LDSA_H + (wm + mt * 16 + mfrag) * 32 + chA];
            al[mt] = *(const bf16x8*)&lds[LDSA_L + (wm + mt * 16 + mfrag) * 32 + chA];
        }
#pragma unroll
        for (int nt = 0; nt < 4; ++nt)
            bh[nt] = *(const bf16x8*)&lds[LDSB_H + (wn + nt * 16 + mfrag) * 32 + chA];

#pragma unroll
        for (int mt = 0; mt < 4; ++mt)
#pragma unroll
            for (int nt = 0; nt < 4; ++nt) {
                acc[mt][nt] = __builtin_amdgcn_mfma_f32_16x16x32_bf16(
                    ah[mt], bh[nt], acc[mt][nt], 0, 0, 0);
                acc[mt][nt] = __builtin_amdgcn_mfma_f32_16x16x32_bf16(
                    al[mt], bh[nt], acc[mt][nt], 0, 0, 0);
            }
    }

    float bcol[4];
#pragma unroll
    for (int nt = 0; nt < 4; ++nt) bcol[nt] = bias[n0 + wn + nt * 16 + mfrag];

    if (MODE == 0) {
        const int which = n0 >> 11;          // 0=q 1=k 2=v
        const int h     = (n0 & 2047) >> 7;
        const int bidx  = m0 >> 11;
        if (which < 2) {
#pragma unroll
            for (int mt = 0; mt < 4; ++mt)
#pragma unroll
                for (int r = 0; r < 4; ++r) {
                    int sl = (m0 & 2047) + wm + mt * 16 + 4 * quad + r;
#pragma unroll
                    for (int nt = 0; nt < 4; ++nt) {
                        float x  = acc[mt][nt][r] + bcol[nt];
                        float px = __shfl_xor(x, 1, 64);   // RoPE pair partner
                        int   d  = wn + nt * 16 + mfrag;
                        float c  = ct[sl * 64 + (d >> 1)];
                        float sn = st[sl * 64 + (d >> 1)];
                        float rot = (mfrag & 1) ? fmaf(px, sn, x * c)
                                                : (x * c - px * sn);
                        size_t off = ((size_t)(bidx * NH + h) * SEQ + sl) * HD + d;
                        if (which == 0) {
                            short hv = f2bf(rot);
                            qhi[off] = hv;
                            qlo[off] = f2bf(rot - bf2f(hv));
                        } else {
                            kbf[off] = f2bf(rot);
                        }
                    }
                }
        } else {
            // V: per-wave LDS transpose -> vT [b][h][d][s]
            __syncthreads();   // staging reads done; reuse LDS (uniform: per-block which)
            short* tw = &lds[w * 4608];      // 64 x 72 shorts, wave-private
#pragma unroll
            for (int mt = 0; mt < 4; ++mt)
#pragma unroll
                for (int nt = 0; nt < 4; ++nt)
#pragma unroll
                    for (int r = 0; r < 4; ++r)
                        tw[(nt * 16 + mfrag) * 72 + (mt * 16 + 4 * quad + r)] =
                            f2bf(acc[mt][nt][r] + bcol[nt]);
            const size_t vbase = (size_t)(bidx * NH + h) * HD * SEQ;
            const int sbase = (m0 & 2047) + wm;
#pragma unroll
            for (int it = 0; it < 8; ++it) {
                int dl  = it * 8 + (lane >> 3);
                int cch = (lane & 7) ^ (lane >> 3);       // bank-spread chunk
                bf16x8 row = *(const bf16x8*)&tw[dl * 72 + cch * 8];
                *(bf16x8*)(vTt + vbase + (size_t)(wn + dl) * SEQ + sbase + cch * 8) = row;
            }
        }
    } else {
#pragma unroll
        for (int mt = 0; mt < 4; ++mt)
#pragma unroll
            for (int r = 0; r < 4; ++r) {
                int m = m0 + wm + mt * 16 + 4 * quad + r;
#pragma unroll
                for (int nt = 0; nt < 4; ++nt)
                    C[(size_t)m * HID + n0 + wn + nt * 16 + mfrag] =
                        acc[mt][nt][r] + bcol[nt];
            }
    }
}

// ---------------------------------------------------------------------------
// MFMA flash attention (R4 structure). Outputs ctx as hi/lo bf16 for the
// out-proj MFMA GEMM.
// ---------------------------------------------------------------------------
__global__ __launch_bounds__(256, 3) void attn_mfma_kernel(
    const short* __restrict__ qhi, const short* __restrict__ qlo,
    const short* __restrict__ kbf, const short* __restrict__ vTt,
    const float* __restrict__ mask,
    short* __restrict__ ctxh, short* __restrict__ ctxl) {
    __shared__ __align__(16) short Pw[4][16][72];

    const int t    = threadIdx.x;
    const int w    = t >> 6;
    const int lane = t & 63;
    const int m    = lane & 15;
    const int quad = lane >> 4;
    const int q0   = blockIdx.x * 64;
    const int bh   = blockIdx.y;
    const int b    = bh >> 4;
    const int h    = bh & 15;

    const size_t base = (size_t)bh * SEQ * HD;
    const short* kp = kbf + base;
    const short* vp = vTt + base;
    const float* mrow = mask + (size_t)b * SEQ;

    const int srow = q0 + w * 16 + m;
    bf16x8 qh[4], ql[4];
    {
        const short* qhp = qhi + base + (size_t)srow * HD;
        const short* qlp = qlo + base + (size_t)srow * HD;
#pragma unroll
        for (int c = 0; c < 4; ++c) {
            qh[c] = *(const bf16x8*)(qhp + 32 * c + 8 * quad);
            ql[c] = *(const bf16x8*)(qlp + 32 * c + 8 * quad);
        }
    }

    const float scale = 0.08838834764831845f;
    f32x4 O[8];
    float m_i[4], l_i[4];
#pragma unroll
    for (int c = 0; c < 8; ++c) O[c] = (f32x4){0.f, 0.f, 0.f, 0.f};
#pragma unroll
    for (int r = 0; r < 4; ++r) { m_i[r] = -INFINITY; l_i[r] = 0.f; }

    for (int kt = 0; kt < SEQ / 64; ++kt) {
        const int k0 = kt * 64;

        float mk[4];
#pragma unroll
        for (int c2 = 0; c2 < 4; ++c2) mk[c2] = mrow[k0 + 16 * c2 + m];

        f32x4 S[4];
#pragma unroll
        for (int c2 = 0; c2 < 4; ++c2) {
            f32x4 acc = (f32x4){0.f, 0.f, 0.f, 0.f};
            const short* krow = kp + (size_t)(k0 + 16 * c2 + m) * HD + 8 * quad;
#pragma unroll
            for (int c = 0; c < 4; ++c) {
                bf16x8 kf = *(const bf16x8*)(krow + 32 * c);
                acc = __builtin_amdgcn_mfma_f32_16x16x32_bf16(qh[c], kf, acc, 0, 0, 0);
                acc = __builtin_amdgcn_mfma_f32_16x16x32_bf16(ql[c], kf, acc, 0, 0, 0);
            }
            S[c2] = acc;
        }

        float alpha[4], p[4][4];
#pragma unroll
        for (int r = 0; r < 4; ++r) {
            float s0 = S[0][r] * scale + mk[0];
            float s1 = S[1][r] * scale + mk[1];
            float s2 = S[2][r] * scale + mk[2];
            float s3 = S[3][r] * scale + mk[3];
            float rm = fmaxf(fmaxf(s0, s1), fmaxf(s2, s3));
#pragma unroll
            for (int off = 1; off < 16; off <<= 1)
                rm = fmaxf(rm, __shfl_xor(rm, off, 64));
            float mn = fmaxf(m_i[r], rm);
            alpha[r] = __expf(m_i[r] - mn);
            p[0][r] = __expf(s0 - mn);
            p[1][r] = __expf(s1 - mn);
            p[2][r] = __expf(s2 - mn);
            p[3][r] = __expf(s3 - mn);
            float ts = (p[0][r] + p[1][r]) + (p[2][r] + p[3][r]);
#pragma unroll
            for (int off = 1; off < 16; off <<= 1)
                ts += __shfl_xor(ts, off, 64);
            l_i[r] = l_i[r] * alpha[r] + ts;
            m_i[r] = mn;
        }

#pragma unroll
        for (int c2 = 0; c2 < 4; ++c2)
#pragma unroll
            for (int r = 0; r < 4; ++r)
                Pw[w][4 * quad + r][16 * c2 + m] = f2bf(p[c2][r]);

#pragma unroll
        for (int c = 0; c < 8; ++c)
#pragma unroll
            for (int r = 0; r < 4; ++r) O[c][r] *= alpha[r];

#pragma unroll
        for (int cc = 0; cc < 2; ++cc) {
            bf16x8 pf = *(const bf16x8*)&Pw[w][m][32 * cc + 8 * quad];
#pragma unroll
            for (int c = 0; c < 8; ++c) {
                bf16x8 vf = *(const bf16x8*)(vp + (size_t)(16 * c + m) * SEQ +
                                             k0 + 32 * cc + 8 * quad);
                O[c] = __builtin_amdgcn_mfma_f32_16x16x32_bf16(pf, vf, O[c], 0, 0, 0);
            }
        }
    }

#pragma unroll
    for (int r = 0; r < 4; ++r) {
        float inv = 1.0f / l_i[r];
        int s = q0 + w * 16 + 4 * quad + r;
        size_t off = ((size_t)(b * SEQ + s)) * HID + h * HD;
#pragma unroll
        for (int c = 0; c < 8; ++c) {
            float val = O[c][r] * inv;
            short hv = f2bf(val);
            ctxh[off + 16 * c + m] = hv;
            ctxl[off + 16 * c + m] = f2bf(val - bf2f(hv));
        }
    }
}

// ---------------------------------------------------------------------------
extern "C" void kernel_launch(void* const* d_in, const int* in_sizes, int n_in,
                              void* d_out, int out_size, void* d_ws, size_t ws_size,
                              hipStream_t stream) {
    const float* hs   = (const float*)d_in[0];
    const float* mask = (const float*)d_in[1];
    const float* Wqkv = (const float*)d_in[2];
    const float* bqkv = (const float*)d_in[3];
    const float* Wout = (const float*)d_in[4];
    const float* bout = (const float*)d_in[5];
    float* out = (float*)d_out;

    const size_t qkv_elems = (size_t)NBATCH * NH * SEQ * HD;  // 8.39M
    char* p = (char*)d_ws;
    float* cos_t = (float*)p; p += (size_t)SEQ * 64 * 4;
    float* sin_t = (float*)p; p += (size_t)SEQ * 64 * 4;
    short* qhi   = (short*)p; p += qkv_elems * 2;
    short* qlo   = (short*)p; p += qkv_elems * 2;
    short* kbf   = (short*)p; p += qkv_elems * 2;
    short* vTt   = (short*)p; p += qkv_elems * 2;
    short* Wqkvh = (short*)p; p += (size_t)3 * HID * HID * 2;
    short* Wouth = (short*)p; p += (size_t)HID * HID * 2;
    short* Ah    = (short*)p; p += qkv_elems * 2;   // aliased: ctxh after QKV GEMM
    short* Al    = (short*)p; p += qkv_elems * 2;   // aliased: ctxl
    short* ctxh  = Ah;
    short* ctxl  = Al;

    rope_table_kernel<<<(SEQ * 64 + 255) / 256, 256, 0, stream>>>(cos_t, sin_t);

    // precision splits
    split_hl_kernel<<<(int)(qkv_elems / 4 / 256), 256, 0, stream>>>(hs, Ah, Al,
                                                                    (int)(qkv_elems / 4));
    split_h_kernel<<<(int)((size_t)3 * HID * HID / 4 / 256), 256, 0, stream>>>(
        Wqkv, Wqkvh, (int)((size_t)3 * HID * HID / 4));
    split_h_kernel<<<(int)((size_t)HID * HID / 4 / 256), 256, 0, stream>>>(
        Wout, Wouth, (int)((size_t)HID * HID / 4));

    // QKV: M=4096, N=6144, K=2048 (bf16 MFMA, 2-chain)
    gemm_bf16_kernel<0><<<dim3(48, 32), 256, 0, stream>>>(
        Ah, Al, Wqkvh, bqkv, nullptr, qhi, qlo, kbf, vTt, cos_t, sin_t);

    // attention
    attn_mfma_kernel<<<dim3(SEQ / 64, NH * NBATCH), 256, 0, stream>>>(
        qhi, qlo, kbf, vTt, mask, ctxh, ctxl);

    // out-proj: M=4096, N=2048, K=2048
    gemm_bf16_kernel<1><<<dim3(16, 32), 256, 0, stream>>>(
        ctxh, ctxl, Wouth, bout, out, nullptr, nullptr, nullptr, nullptr,
        nullptr, nullptr);
}

// Round 6
// 615.370 us; speedup vs baseline: 5.4425x; 1.4654x over previous
//
#include <hip/hip_runtime.h>
#include <math.h>

#define HID    2048
#define NH     16
#define HD     128
#define SEQ    2048
#define NBATCH 2

typedef __attribute__((ext_vector_type(8))) short bf16x8;   // 8 bf16 = 4 VGPRs
typedef __attribute__((ext_vector_type(4))) float f32x4;    // MFMA accumulator

__device__ __forceinline__ short f2bf(float f) {            // fp32 -> bf16 RNE
    union { float f; unsigned u; } x; x.f = f;
    unsigned r = x.u + 0x7fffu + ((x.u >> 16) & 1u);
    return (short)(r >> 16);
}
__device__ __forceinline__ float bf2f(short s) {
    union { unsigned u; float f; } y;
    y.u = ((unsigned)(unsigned short)s) << 16;
    return y.f;
}

// async global->LDS, 16 B per lane; LDS dest = wave-uniform base + lane*16
__device__ __forceinline__ void gl_lds16(const short* g, short* l) {
    __builtin_amdgcn_global_load_lds(
        (const __attribute__((address_space(1))) unsigned int*)g,
        (__attribute__((address_space(3))) unsigned int*)l, 16, 0, 0);
}

// ---------------------------------------------------------------------------
// RoPE tables
// ---------------------------------------------------------------------------
__global__ __launch_bounds__(256) void rope_table_kernel(float* __restrict__ ct,
                                                         float* __restrict__ st) {
    int idx = blockIdx.x * 256 + threadIdx.x;
    if (idx >= SEQ * 64) return;
    int s = idx >> 6;
    int i = idx & 63;
    double inv = pow(10000.0, -(double)i / 64.0);
    float freq = (float)s * (float)inv;
    ct[idx] = cosf(freq);
    st[idx] = sinf(freq);
}

// ---------------------------------------------------------------------------
// fp32 -> bf16 hi+lo split (A operands) and hi-only (weights)
// ---------------------------------------------------------------------------
__global__ __launch_bounds__(256) void split_hl_kernel(const float* __restrict__ in,
                                                       short* __restrict__ oh,
                                                       short* __restrict__ ol, int n4) {
    int i = blockIdx.x * 256 + threadIdx.x;
    if (i >= n4) return;
    float4 v = ((const float4*)in)[i];
    short4 h, l;
    h.x = f2bf(v.x); l.x = f2bf(v.x - bf2f(h.x));
    h.y = f2bf(v.y); l.y = f2bf(v.y - bf2f(h.y));
    h.z = f2bf(v.z); l.z = f2bf(v.z - bf2f(h.z));
    h.w = f2bf(v.w); l.w = f2bf(v.w - bf2f(h.w));
    *(short4*)(oh + 4 * (size_t)i) = h;
    *(short4*)(ol + 4 * (size_t)i) = l;
}

__global__ __launch_bounds__(256) void split_h_kernel(const float* __restrict__ in,
                                                      short* __restrict__ oh, int n4) {
    int i = blockIdx.x * 256 + threadIdx.x;
    if (i >= n4) return;
    float4 v = ((const float4*)in)[i];
    short4 h;
    h.x = f2bf(v.x); h.y = f2bf(v.y); h.z = f2bf(v.z); h.w = f2bf(v.w);
    *(short4*)(oh + 4 * (size_t)i) = h;
}

// ---------------------------------------------------------------------------
// bf16 MFMA GEMM (unchanged from R5): C = (Ah+Al).Wh^T + bias
// ---------------------------------------------------------------------------
#define LDSA_H 0
#define LDSA_L 4096
#define LDSB_H 8192

template <int MODE>
__global__ __launch_bounds__(256, 2) void gemm_bf16_kernel(
    const short* __restrict__ Ah, const short* __restrict__ Al,
    const short* __restrict__ Bh, const float* __restrict__ bias,
    float* __restrict__ C,
    short* __restrict__ qhi, short* __restrict__ qlo,
    short* __restrict__ kbf, short* __restrict__ vTt,
    const float* __restrict__ ct, const float* __restrict__ st) {
    __shared__ short lds[18432];

    const int t     = threadIdx.x;
    const int w     = t >> 6;
    const int lane  = t & 63;
    const int mfrag = lane & 15;
    const int quad  = lane >> 4;
    const int wm    = (w >> 1) * 64;
    const int wn    = (w & 1) * 64;
    const int m0    = blockIdx.y * 128;
    const int n0    = blockIdx.x * 128;

    const int srow   = lane >> 2;
    const int schunk = (((lane & 3) ^ ((lane >> 3) & 3))) * 8;
    const short* gA0 = Ah + (size_t)(m0 + w * 16 + srow) * HID + schunk;
    const short* gA1 = Ah + (size_t)(m0 + 64 + w * 16 + srow) * HID + schunk;
    const short* gL0 = Al + (size_t)(m0 + w * 16 + srow) * HID + schunk;
    const short* gL1 = Al + (size_t)(m0 + 64 + w * 16 + srow) * HID + schunk;
    const short* gB0 = Bh + (size_t)(n0 + w * 16 + srow) * HID + schunk;
    const short* gB1 = Bh + (size_t)(n0 + 64 + w * 16 + srow) * HID + schunk;
    short* lA0 = &lds[LDSA_H + (w * 16) * 32];
    short* lA1 = &lds[LDSA_H + (64 + w * 16) * 32];
    short* lL0 = &lds[LDSA_L + (w * 16) * 32];
    short* lL1 = &lds[LDSA_L + (64 + w * 16) * 32];
    short* lB0 = &lds[LDSB_H + (w * 16) * 32];
    short* lB1 = &lds[LDSB_H + (64 + w * 16) * 32];

    const int chA = 8 * (quad ^ ((mfrag >> 1) & 3));

    f32x4 acc[4][4];
#pragma unroll
    for (int i = 0; i < 4; ++i)
#pragma unroll
        for (int j = 0; j < 4; ++j) acc[i][j] = (f32x4){0.f, 0.f, 0.f, 0.f};

    for (int kt = 0; kt < HID; kt += 32) {
        __syncthreads();
        gl_lds16(gA0 + kt, lA0);
        gl_lds16(gA1 + kt, lA1);
        gl_lds16(gL0 + kt, lL0);
        gl_lds16(gL1 + kt, lL1);
        gl_lds16(gB0 + kt, lB0);
        gl_lds16(gB1 + kt, lB1);
        __syncthreads();

        bf16x8 ah[4], al[4], bh[4];
#pragma unroll
        for (int mt = 0; mt < 4; ++mt) {
            ah[mt] = *(const bf16x8*)&lds[LDSA_H + (wm + mt * 16 + mfrag) * 32 + chA];
            al[mt] = *(const bf16x8*)&lds[LDSA_L + (wm + mt * 16 + mfrag) * 32 + chA];
        }
#pragma unroll
        for (int nt = 0; nt < 4; ++nt)
            bh[nt] = *(const bf16x8*)&lds[LDSB_H + (wn + nt * 16 + mfrag) * 32 + chA];

#pragma unroll
        for (int mt = 0; mt < 4; ++mt)
#pragma unroll
            for (int nt = 0; nt < 4; ++nt) {
                acc[mt][nt] = __builtin_amdgcn_mfma_f32_16x16x32_bf16(
                    ah[mt], bh[nt], acc[mt][nt], 0, 0, 0);
                acc[mt][nt] = __builtin_amdgcn_mfma_f32_16x16x32_bf16(
                    al[mt], bh[nt], acc[mt][nt], 0, 0, 0);
            }
    }

    float bcol[4];
#pragma unroll
    for (int nt = 0; nt < 4; ++nt) bcol[nt] = bias[n0 + wn + nt * 16 + mfrag];

    if (MODE == 0) {
        const int which = n0 >> 11;
        const int h     = (n0 & 2047) >> 7;
        const int bidx  = m0 >> 11;
        if (which < 2) {
#pragma unroll
            for (int mt = 0; mt < 4; ++mt)
#pragma unroll
                for (int r = 0; r < 4; ++r) {
                    int sl = (m0 & 2047) + wm + mt * 16 + 4 * quad + r;
#pragma unroll
                    for (int nt = 0; nt < 4; ++nt) {
                        float x  = acc[mt][nt][r] + bcol[nt];
                        float px = __shfl_xor(x, 1, 64);
                        int   d  = wn + nt * 16 + mfrag;
                        float c  = ct[sl * 64 + (d >> 1)];
                        float sn = st[sl * 64 + (d >> 1)];
                        float rot = (mfrag & 1) ? fmaf(px, sn, x * c)
                                                : (x * c - px * sn);
                        size_t off = ((size_t)(bidx * NH + h) * SEQ + sl) * HD + d;
                        if (which == 0) {
                            short hv = f2bf(rot);
                            qhi[off] = hv;
                            qlo[off] = f2bf(rot - bf2f(hv));
                        } else {
                            kbf[off] = f2bf(rot);
                        }
                    }
                }
        } else {
            __syncthreads();
            short* tw = &lds[w * 4608];
#pragma unroll
            for (int mt = 0; mt < 4; ++mt)
#pragma unroll
                for (int nt = 0; nt < 4; ++nt)
#pragma unroll
                    for (int r = 0; r < 4; ++r)
                        tw[(nt * 16 + mfrag) * 72 + (mt * 16 + 4 * quad + r)] =
                            f2bf(acc[mt][nt][r] + bcol[nt]);
            const size_t vbase = (size_t)(bidx * NH + h) * HD * SEQ;
            const int sbase = (m0 & 2047) + wm;
#pragma unroll
            for (int it = 0; it < 8; ++it) {
                int dl  = it * 8 + (lane >> 3);
                int cch = (lane & 7) ^ (lane >> 3);
                bf16x8 row = *(const bf16x8*)&tw[dl * 72 + cch * 8];
                *(bf16x8*)(vTt + vbase + (size_t)(wn + dl) * SEQ + sbase + cch * 8) = row;
            }
        }
    } else {
#pragma unroll
        for (int mt = 0; mt < 4; ++mt)
#pragma unroll
            for (int r = 0; r < 4; ++r) {
                int m = m0 + wm + mt * 16 + 4 * quad + r;
#pragma unroll
                for (int nt = 0; nt < 4; ++nt)
                    C[(size_t)m * HID + n0 + wn + nt * 16 + mfrag] =
                        acc[mt][nt][r] + bcol[nt];
            }
    }
}

// ---------------------------------------------------------------------------
// MFMA flash attention with LDS-staged K/V (m97 pattern).
// Block = 4 waves; q-tile 64 (16 rows/wave); KV tile 64.
// K tile [kj][d] 64x128 bf16 (16 KB), V^T tile [d][s] 128x64 bf16 (16 KB),
// staged via global_load_lds w=16 with XOR-swizzled 16B granules
// (phys chunk = logical ^ (row&7)) so ds_read_b128 fragments are 2-way (free).
// LDS 41 KB -> 3 blocks/CU.
// ---------------------------------------------------------------------------
#define LDSK 0
#define LDSV 8192
#define LDSP 16384

__global__ __launch_bounds__(256, 3) void attn_mfma_kernel(
    const short* __restrict__ qhi, const short* __restrict__ qlo,
    const short* __restrict__ kbf, const short* __restrict__ vTt,
    const float* __restrict__ mask,
    short* __restrict__ ctxh, short* __restrict__ ctxl) {
    __shared__ __align__(16) short lds[20992];   // K 8192 | V 8192 | P 4608

    const int t    = threadIdx.x;
    const int w    = t >> 6;
    const int lane = t & 63;
    const int m    = lane & 15;
    const int quad = lane >> 4;
    const int q0   = blockIdx.x * 64;
    const int bh   = blockIdx.y;
    const int b    = bh >> 4;
    const int h    = bh & 15;

    const size_t base = (size_t)bh * SEQ * HD;
    const short* kp = kbf + base;        // [s][d]
    const short* vp = vTt + base;        // [d][s]
    const float* mrow = mask + (size_t)b * SEQ;

    // staging addresses (swizzled source granule; LDS dest lane-contiguous)
    size_t kOff[4], vOff[4];
    short *ldsK[4], *ldsV[4];
#pragma unroll
    for (int u = 0; u < 4; ++u) {
        int rk = w * 16 + u * 4 + (lane >> 4);           // K row 0..63
        int ck = (lane & 15) ^ (rk & 7);                 // granule swizzle
        kOff[u] = (size_t)rk * HD + ck * 8;
        ldsK[u] = &lds[LDSK + (w * 16 + u * 4) * 128];
        int rv = w * 32 + u * 8 + (lane >> 3);           // V row (d) 0..127
        int cv = (lane & 7) ^ (rv & 7);
        vOff[u] = (size_t)rv * SEQ + cv * 8;
        ldsV[u] = &lds[LDSV + (w * 32 + u * 8) * 64];
    }

    // Q fragments (16 rows/wave), direct global, once
    const int srow = q0 + w * 16 + m;
    bf16x8 qh[4], ql[4];
    {
        const short* qhp = qhi + base + (size_t)srow * HD;
        const short* qlp = qlo + base + (size_t)srow * HD;
#pragma unroll
        for (int c = 0; c < 4; ++c) {
            qh[c] = *(const bf16x8*)(qhp + 32 * c + 8 * quad);
            ql[c] = *(const bf16x8*)(qlp + 32 * c + 8 * quad);
        }
    }

    const float scale = 0.08838834764831845f;
    f32x4 O[8];
    float m_i[4], l_i[4];
#pragma unroll
    for (int c = 0; c < 8; ++c) O[c] = (f32x4){0.f, 0.f, 0.f, 0.f};
#pragma unroll
    for (int r = 0; r < 4; ++r) { m_i[r] = -INFINITY; l_i[r] = 0.f; }

    const int sw = m & 7;     // fragment-read inverse swizzle key

    for (int kt = 0; kt < SEQ / 64; ++kt) {
        const int k0 = kt * 64;

        __syncthreads();   // prior tile's LDS reads done
#pragma unroll
        for (int u = 0; u < 4; ++u) {
            gl_lds16(kp + (size_t)k0 * HD + kOff[u], ldsK[u]);
            gl_lds16(vp + k0 + vOff[u], ldsV[u]);
        }
        __syncthreads();   // staged data visible (vmcnt drained)

        float mk[4];
#pragma unroll
        for (int c2 = 0; c2 < 4; ++c2) mk[c2] = mrow[k0 + 16 * c2 + m];

        // ---- QK^T from LDS ----
        f32x4 S[4];
#pragma unroll
        for (int c2 = 0; c2 < 4; ++c2) {
            f32x4 acc = (f32x4){0.f, 0.f, 0.f, 0.f};
#pragma unroll
            for (int c = 0; c < 4; ++c) {
                int pk = (4 * c + quad) ^ sw;
                bf16x8 kf = *(const bf16x8*)&lds[LDSK + (16 * c2 + m) * 128 + pk * 8];
                acc = __builtin_amdgcn_mfma_f32_16x16x32_bf16(qh[c], kf, acc, 0, 0, 0);
                acc = __builtin_amdgcn_mfma_f32_16x16x32_bf16(ql[c], kf, acc, 0, 0, 0);
            }
            S[c2] = acc;
        }

        // ---- online softmax ----
        float alpha[4], p[4][4];
#pragma unroll
        for (int r = 0; r < 4; ++r) {
            float s0 = S[0][r] * scale + mk[0];
            float s1 = S[1][r] * scale + mk[1];
            float s2 = S[2][r] * scale + mk[2];
            float s3 = S[3][r] * scale + mk[3];
            float rm = fmaxf(fmaxf(s0, s1), fmaxf(s2, s3));
#pragma unroll
            for (int off = 1; off < 16; off <<= 1)
                rm = fmaxf(rm, __shfl_xor(rm, off, 64));
            float mn = fmaxf(m_i[r], rm);
            alpha[r] = __expf(m_i[r] - mn);
            p[0][r] = __expf(s0 - mn);
            p[1][r] = __expf(s1 - mn);
            p[2][r] = __expf(s2 - mn);
            p[3][r] = __expf(s3 - mn);
            float ts = (p[0][r] + p[1][r]) + (p[2][r] + p[3][r]);
#pragma unroll
            for (int off = 1; off < 16; off <<= 1)
                ts += __shfl_xor(ts, off, 64);
            l_i[r] = l_i[r] * alpha[r] + ts;
            m_i[r] = mn;
        }

        // ---- P: C-layout -> A-layout via wave-private LDS ----
#pragma unroll
        for (int c2 = 0; c2 < 4; ++c2)
#pragma unroll
            for (int r = 0; r < 4; ++r)
                lds[LDSP + w * 1152 + (4 * quad + r) * 72 + 16 * c2 + m] =
                    f2bf(p[c2][r]);

        // ---- rescale O, then PV from LDS ----
#pragma unroll
        for (int c = 0; c < 8; ++c)
#pragma unroll
            for (int r = 0; r < 4; ++r) O[c][r] *= alpha[r];

#pragma unroll
        for (int cc = 0; cc < 2; ++cc) {
            bf16x8 pf = *(const bf16x8*)&lds[LDSP + w * 1152 + m * 72 +
                                             32 * cc + 8 * quad];
#pragma unroll
            for (int c = 0; c < 8; ++c) {
                int pv = (4 * cc + quad) ^ sw;
                bf16x8 vf = *(const bf16x8*)&lds[LDSV + (16 * c + m) * 64 + pv * 8];
                O[c] = __builtin_amdgcn_mfma_f32_16x16x32_bf16(pf, vf, O[c], 0, 0, 0);
            }
        }
    }

    // ---- epilogue: ctx hi/lo bf16 ----
#pragma unroll
    for (int r = 0; r < 4; ++r) {
        float inv = 1.0f / l_i[r];
        int s = q0 + w * 16 + 4 * quad + r;
        size_t off = ((size_t)(b * SEQ + s)) * HID + h * HD;
#pragma unroll
        for (int c = 0; c < 8; ++c) {
            float val = O[c][r] * inv;
            short hv = f2bf(val);
            ctxh[off + 16 * c + m] = hv;
            ctxl[off + 16 * c + m] = f2bf(val - bf2f(hv));
        }
    }
}

// ---------------------------------------------------------------------------
extern "C" void kernel_launch(void* const* d_in, const int* in_sizes, int n_in,
                              void* d_out, int out_size, void* d_ws, size_t ws_size,
                              hipStream_t stream) {
    const float* hs   = (const float*)d_in[0];
    const float* mask = (const float*)d_in[1];
    const float* Wqkv = (const float*)d_in[2];
    const float* bqkv = (const float*)d_in[3];
    const float* Wout = (const float*)d_in[4];
    const float* bout = (const float*)d_in[5];
    float* out = (float*)d_out;

    const size_t qkv_elems = (size_t)NBATCH * NH * SEQ * HD;  // 8.39M
    char* p = (char*)d_ws;
    float* cos_t = (float*)p; p += (size_t)SEQ * 64 * 4;
    float* sin_t = (float*)p; p += (size_t)SEQ * 64 * 4;
    short* qhi   = (short*)p; p += qkv_elems * 2;
    short* qlo   = (short*)p; p += qkv_elems * 2;
    short* kbf   = (short*)p; p += qkv_elems * 2;
    short* vTt   = (short*)p; p += qkv_elems * 2;
    short* Wqkvh = (short*)p; p += (size_t)3 * HID * HID * 2;
    short* Wouth = (short*)p; p += (size_t)HID * HID * 2;
    short* Ah    = (short*)p; p += qkv_elems * 2;   // aliased: ctxh after QKV GEMM
    short* Al    = (short*)p; p += qkv_elems * 2;   // aliased: ctxl
    short* ctxh  = Ah;
    short* ctxl  = Al;

    rope_table_kernel<<<(SEQ * 64 + 255) / 256, 256, 0, stream>>>(cos_t, sin_t);

    split_hl_kernel<<<(int)(qkv_elems / 4 / 256), 256, 0, stream>>>(hs, Ah, Al,
                                                                    (int)(qkv_elems / 4));
    split_h_kernel<<<(int)((size_t)3 * HID * HID / 4 / 256), 256, 0, stream>>>(
        Wqkv, Wqkvh, (int)((size_t)3 * HID * HID / 4));
    split_h_kernel<<<(int)((size_t)HID * HID / 4 / 256), 256, 0, stream>>>(
        Wout, Wouth, (int)((size_t)HID * HID / 4));

    // QKV: M=4096, N=6144, K=2048 (bf16 MFMA, 2-chain)
    gemm_bf16_kernel<0><<<dim3(48, 32), 256, 0, stream>>>(
        Ah, Al, Wqkvh, bqkv, nullptr, qhi, qlo, kbf, vTt, cos_t, sin_t);

    // attention
    attn_mfma_kernel<<<dim3(SEQ / 64, NH * NBATCH), 256, 0, stream>>>(
        qhi, qlo, kbf, vTt, mask, ctxh, ctxl);

    // out-proj: M=4096, N=2048, K=2048
    gemm_bf16_kernel<1><<<dim3(16, 32), 256, 0, stream>>>(
        ctxh, ctxl, Wouth, bout, out, nullptr, nullptr, nullptr, nullptr,
        nullptr, nullptr);
}

// Round 7
// 479.992 us; speedup vs baseline: 6.9775x; 1.2820x over previous
//
#include <hip/hip_runtime.h>
#include <math.h>

#define HID    2048
#define NH     16
#define HD     128
#define SEQ    2048
#define NBATCH 2

typedef __attribute__((ext_vector_type(8))) short bf16x8;   // 8 bf16 = 4 VGPRs
typedef __attribute__((ext_vector_type(4))) float f32x4;    // MFMA accumulator

__device__ __forceinline__ short f2bf(float f) {            // fp32 -> bf16 RNE
    union { float f; unsigned u; } x; x.f = f;
    unsigned r = x.u + 0x7fffu + ((x.u >> 16) & 1u);
    return (short)(r >> 16);
}
__device__ __forceinline__ float bf2f(short s) {
    union { unsigned u; float f; } y;
    y.u = ((unsigned)(unsigned short)s) << 16;
    return y.f;
}

// async global->LDS, 16 B per lane; LDS dest = wave-uniform base + lane*16
__device__ __forceinline__ void gl_lds16(const short* g, short* l) {
    __builtin_amdgcn_global_load_lds(
        (const __attribute__((address_space(1))) unsigned int*)g,
        (__attribute__((address_space(3))) unsigned int*)l, 16, 0, 0);
}

// ---------------------------------------------------------------------------
// RoPE tables
// ---------------------------------------------------------------------------
__global__ __launch_bounds__(256) void rope_table_kernel(float* __restrict__ ct,
                                                         float* __restrict__ st) {
    int idx = blockIdx.x * 256 + threadIdx.x;
    if (idx >= SEQ * 64) return;
    int s = idx >> 6;
    int i = idx & 63;
    double inv = pow(10000.0, -(double)i / 64.0);
    float freq = (float)s * (float)inv;
    ct[idx] = cosf(freq);
    st[idx] = sinf(freq);
}

// ---------------------------------------------------------------------------
// fp32 -> bf16 (RNE) cast
// ---------------------------------------------------------------------------
__global__ __launch_bounds__(256) void split_h_kernel(const float* __restrict__ in,
                                                      short* __restrict__ oh, int n4) {
    int i = blockIdx.x * 256 + threadIdx.x;
    if (i >= n4) return;
    float4 v = ((const float4*)in)[i];
    short4 h;
    h.x = f2bf(v.x); h.y = f2bf(v.y); h.z = f2bf(v.z); h.w = f2bf(v.w);
    *(short4*)(oh + 4 * (size_t)i) = h;
}

// ---------------------------------------------------------------------------
// bf16 MFMA GEMM (m97 structure): C = A.B^T + bias, single bf16 chain.
// 128x128 tile, BK=32, 4 waves (2x2 of 64x64), 4x4 16x16x32 MFMAs.
// global_load_lds w=16 staging, XOR-swizzled granules (2-way frag reads).
// MODE 0: QKV -> RoPE (shfl pair) -> qb/kbf [b][h][s][d] bf16 + vT [b][h][d][s]
// MODE 1: out-proj -> fp32 C
// ---------------------------------------------------------------------------
#define LDSA 0
#define LDSB 4096

template <int MODE>
__global__ __launch_bounds__(256, 3) void gemm_bf16_kernel(
    const short* __restrict__ Ah, const short* __restrict__ Bh,
    const float* __restrict__ bias, float* __restrict__ C,
    short* __restrict__ qb, short* __restrict__ kbf, short* __restrict__ vTt,
    const float* __restrict__ ct, const float* __restrict__ st) {
    __shared__ short lds[MODE == 0 ? 18432 : 8192];  // staging 16 KB; V-transp 36 KB

    const int t     = threadIdx.x;
    const int w     = t >> 6;
    const int lane  = t & 63;
    const int mfrag = lane & 15;
    const int quad  = lane >> 4;
    const int wm    = (w >> 1) * 64;
    const int wn    = (w & 1) * 64;
    const int m0    = blockIdx.y * 128;
    const int n0    = blockIdx.x * 128;

    const int srow   = lane >> 2;
    const int schunk = (((lane & 3) ^ ((lane >> 3) & 3))) * 8;
    const short* gA0 = Ah + (size_t)(m0 + w * 16 + srow) * HID + schunk;
    const short* gA1 = Ah + (size_t)(m0 + 64 + w * 16 + srow) * HID + schunk;
    const short* gB0 = Bh + (size_t)(n0 + w * 16 + srow) * HID + schunk;
    const short* gB1 = Bh + (size_t)(n0 + 64 + w * 16 + srow) * HID + schunk;
    short* lA0 = &lds[LDSA + (w * 16) * 32];
    short* lA1 = &lds[LDSA + (64 + w * 16) * 32];
    short* lB0 = &lds[LDSB + (w * 16) * 32];
    short* lB1 = &lds[LDSB + (64 + w * 16) * 32];

    const int chA = 8 * (quad ^ ((mfrag >> 1) & 3));  // inverse swizzle

    f32x4 acc[4][4];
#pragma unroll
    for (int i = 0; i < 4; ++i)
#pragma unroll
        for (int j = 0; j < 4; ++j) acc[i][j] = (f32x4){0.f, 0.f, 0.f, 0.f};

    for (int kt = 0; kt < HID; kt += 32) {
        __syncthreads();
        gl_lds16(gA0 + kt, lA0);
        gl_lds16(gA1 + kt, lA1);
        gl_lds16(gB0 + kt, lB0);
        gl_lds16(gB1 + kt, lB1);
        __syncthreads();

        bf16x8 ah[4], bh[4];
#pragma unroll
        for (int mt = 0; mt < 4; ++mt)
            ah[mt] = *(const bf16x8*)&lds[LDSA + (wm + mt * 16 + mfrag) * 32 + chA];
#pragma unroll
        for (int nt = 0; nt < 4; ++nt)
            bh[nt] = *(const bf16x8*)&lds[LDSB + (wn + nt * 16 + mfrag) * 32 + chA];

#pragma unroll
        for (int mt = 0; mt < 4; ++mt)
#pragma unroll
            for (int nt = 0; nt < 4; ++nt)
                acc[mt][nt] = __builtin_amdgcn_mfma_f32_16x16x32_bf16(
                    ah[mt], bh[nt], acc[mt][nt], 0, 0, 0);
    }

    float bcol[4];
#pragma unroll
    for (int nt = 0; nt < 4; ++nt) bcol[nt] = bias[n0 + wn + nt * 16 + mfrag];

    if (MODE == 0) {
        const int which = n0 >> 11;          // 0=q 1=k 2=v
        const int h     = (n0 & 2047) >> 7;
        const int bidx  = m0 >> 11;
        if (which < 2) {
            short* dst = (which == 0) ? qb : kbf;
#pragma unroll
            for (int mt = 0; mt < 4; ++mt)
#pragma unroll
                for (int r = 0; r < 4; ++r) {
                    int sl = (m0 & 2047) + wm + mt * 16 + 4 * quad + r;
#pragma unroll
                    for (int nt = 0; nt < 4; ++nt) {
                        float x  = acc[mt][nt][r] + bcol[nt];
                        float px = __shfl_xor(x, 1, 64);   // RoPE pair partner
                        int   d  = wn + nt * 16 + mfrag;
                        float c  = ct[sl * 64 + (d >> 1)];
                        float sn = st[sl * 64 + (d >> 1)];
                        float rot = (mfrag & 1) ? fmaf(px, sn, x * c)
                                                : (x * c - px * sn);
                        dst[((size_t)(bidx * NH + h) * SEQ + sl) * HD + d] = f2bf(rot);
                    }
                }
        } else {
            // V: per-wave LDS transpose -> vT [b][h][d][s]
            __syncthreads();   // staging reads done; reuse LDS (which is per-block)
            short* tw = &lds[w * 4608];      // 64 x 72 shorts, wave-private
#pragma unroll
            for (int mt = 0; mt < 4; ++mt)
#pragma unroll
                for (int nt = 0; nt < 4; ++nt)
#pragma unroll
                    for (int r = 0; r < 4; ++r)
                        tw[(nt * 16 + mfrag) * 72 + (mt * 16 + 4 * quad + r)] =
                            f2bf(acc[mt][nt][r] + bcol[nt]);
            const size_t vbase = (size_t)(bidx * NH + h) * HD * SEQ;
            const int sbase = (m0 & 2047) + wm;
#pragma unroll
            for (int it = 0; it < 8; ++it) {
                int dl  = it * 8 + (lane >> 3);
                int cch = (lane & 7) ^ (lane >> 3);
                bf16x8 row = *(const bf16x8*)&tw[dl * 72 + cch * 8];
                *(bf16x8*)(vTt + vbase + (size_t)(wn + dl) * SEQ + sbase + cch * 8) = row;
            }
        }
    } else {
#pragma unroll
        for (int mt = 0; mt < 4; ++mt)
#pragma unroll
            for (int r = 0; r < 4; ++r) {
                int m = m0 + wm + mt * 16 + 4 * quad + r;
#pragma unroll
                for (int nt = 0; nt < 4; ++nt)
                    C[(size_t)m * HID + n0 + wn + nt * 16 + mfrag] =
                        acc[mt][nt][r] + bcol[nt];
            }
    }
}

// ---------------------------------------------------------------------------
// MFMA flash attention with LDS-staged K/V (R6 structure, single-bf16 Q).
// Block = 4 waves; q-tile 64 (16 rows/wave); KV tile 64; LDS 41 KB -> 3 blk/CU.
// ---------------------------------------------------------------------------
#define LDSK 0
#define LDSV 8192
#define LDSP 16384

__global__ __launch_bounds__(256, 3) void attn_mfma_kernel(
    const short* __restrict__ qb, const short* __restrict__ kbf,
    const short* __restrict__ vTt, const float* __restrict__ mask,
    short* __restrict__ ctxb) {
    __shared__ __align__(16) short lds[20992];   // K 8192 | V 8192 | P 4608

    const int t    = threadIdx.x;
    const int w    = t >> 6;
    const int lane = t & 63;
    const int m    = lane & 15;
    const int quad = lane >> 4;
    const int q0   = blockIdx.x * 64;
    const int bh   = blockIdx.y;
    const int b    = bh >> 4;
    const int h    = bh & 15;

    const size_t base = (size_t)bh * SEQ * HD;
    const short* kp = kbf + base;        // [s][d]
    const short* vp = vTt + base;        // [d][s]
    const float* mrow = mask + (size_t)b * SEQ;

    // staging addresses (swizzled source granule; LDS dest lane-contiguous)
    size_t kOff[4], vOff[4];
    short *ldsK[4], *ldsV[4];
#pragma unroll
    for (int u = 0; u < 4; ++u) {
        int rk = w * 16 + u * 4 + (lane >> 4);           // K row 0..63
        int ck = (lane & 15) ^ (rk & 7);                 // granule swizzle
        kOff[u] = (size_t)rk * HD + ck * 8;
        ldsK[u] = &lds[LDSK + (w * 16 + u * 4) * 128];
        int rv = w * 32 + u * 8 + (lane >> 3);           // V row (d) 0..127
        int cv = (lane & 7) ^ (rv & 7);
        vOff[u] = (size_t)rv * SEQ + cv * 8;
        ldsV[u] = &lds[LDSV + (w * 32 + u * 8) * 64];
    }

    // Q fragments (16 rows/wave), direct global, once
    const int srow = q0 + w * 16 + m;
    bf16x8 qh[4];
    {
        const short* qhp = qb + base + (size_t)srow * HD;
#pragma unroll
        for (int c = 0; c < 4; ++c)
            qh[c] = *(const bf16x8*)(qhp + 32 * c + 8 * quad);
    }

    const float scale = 0.08838834764831845f;
    f32x4 O[8];
    float m_i[4], l_i[4];
#pragma unroll
    for (int c = 0; c < 8; ++c) O[c] = (f32x4){0.f, 0.f, 0.f, 0.f};
#pragma unroll
    for (int r = 0; r < 4; ++r) { m_i[r] = -INFINITY; l_i[r] = 0.f; }

    const int sw = m & 7;     // fragment-read inverse swizzle key

    for (int kt = 0; kt < SEQ / 64; ++kt) {
        const int k0 = kt * 64;

        __syncthreads();
#pragma unroll
        for (int u = 0; u < 4; ++u) {
            gl_lds16(kp + (size_t)k0 * HD + kOff[u], ldsK[u]);
            gl_lds16(vp + k0 + vOff[u], ldsV[u]);
        }
        __syncthreads();

        float mk[4];
#pragma unroll
        for (int c2 = 0; c2 < 4; ++c2) mk[c2] = mrow[k0 + 16 * c2 + m];

        // ---- QK^T from LDS (single chain) ----
        f32x4 S[4];
#pragma unroll
        for (int c2 = 0; c2 < 4; ++c2) {
            f32x4 acc = (f32x4){0.f, 0.f, 0.f, 0.f};
#pragma unroll
            for (int c = 0; c < 4; ++c) {
                int pk = (4 * c + quad) ^ sw;
                bf16x8 kf = *(const bf16x8*)&lds[LDSK + (16 * c2 + m) * 128 + pk * 8];
                acc = __builtin_amdgcn_mfma_f32_16x16x32_bf16(qh[c], kf, acc, 0, 0, 0);
            }
            S[c2] = acc;
        }

        // ---- online softmax ----
        float alpha[4], p[4][4];
#pragma unroll
        for (int r = 0; r < 4; ++r) {
            float s0 = S[0][r] * scale + mk[0];
            float s1 = S[1][r] * scale + mk[1];
            float s2 = S[2][r] * scale + mk[2];
            float s3 = S[3][r] * scale + mk[3];
            float rm = fmaxf(fmaxf(s0, s1), fmaxf(s2, s3));
#pragma unroll
            for (int off = 1; off < 16; off <<= 1)
                rm = fmaxf(rm, __shfl_xor(rm, off, 64));
            float mn = fmaxf(m_i[r], rm);
            alpha[r] = __expf(m_i[r] - mn);
            p[0][r] = __expf(s0 - mn);
            p[1][r] = __expf(s1 - mn);
            p[2][r] = __expf(s2 - mn);
            p[3][r] = __expf(s3 - mn);
            float ts = (p[0][r] + p[1][r]) + (p[2][r] + p[3][r]);
#pragma unroll
            for (int off = 1; off < 16; off <<= 1)
                ts += __shfl_xor(ts, off, 64);
            l_i[r] = l_i[r] * alpha[r] + ts;
            m_i[r] = mn;
        }

        // ---- P: C-layout -> A-layout via wave-private LDS ----
#pragma unroll
        for (int c2 = 0; c2 < 4; ++c2)
#pragma unroll
            for (int r = 0; r < 4; ++r)
                lds[LDSP + w * 1152 + (4 * quad + r) * 72 + 16 * c2 + m] =
                    f2bf(p[c2][r]);

        // ---- rescale O, then PV from LDS ----
#pragma unroll
        for (int c = 0; c < 8; ++c)
#pragma unroll
            for (int r = 0; r < 4; ++r) O[c][r] *= alpha[r];

#pragma unroll
        for (int cc = 0; cc < 2; ++cc) {
            bf16x8 pf = *(const bf16x8*)&lds[LDSP + w * 1152 + m * 72 +
                                             32 * cc + 8 * quad];
#pragma unroll
            for (int c = 0; c < 8; ++c) {
                int pv = (4 * cc + quad) ^ sw;
                bf16x8 vf = *(const bf16x8*)&lds[LDSV + (16 * c + m) * 64 + pv * 8];
                O[c] = __builtin_amdgcn_mfma_f32_16x16x32_bf16(pf, vf, O[c], 0, 0, 0);
            }
        }
    }

    // ---- epilogue: ctx bf16 [b][s][h*128+d] ----
#pragma unroll
    for (int r = 0; r < 4; ++r) {
        float inv = 1.0f / l_i[r];
        int s = q0 + w * 16 + 4 * quad + r;
        size_t off = ((size_t)(b * SEQ + s)) * HID + h * HD;
#pragma unroll
        for (int c = 0; c < 8; ++c)
            ctxb[off + 16 * c + m] = f2bf(O[c][r] * inv);
    }
}

// ---------------------------------------------------------------------------
extern "C" void kernel_launch(void* const* d_in, const int* in_sizes, int n_in,
                              void* d_out, int out_size, void* d_ws, size_t ws_size,
                              hipStream_t stream) {
    const float* hs   = (const float*)d_in[0];
    const float* mask = (const float*)d_in[1];
    const float* Wqkv = (const float*)d_in[2];
    const float* bqkv = (const float*)d_in[3];
    const float* Wout = (const float*)d_in[4];
    const float* bout = (const float*)d_in[5];
    float* out = (float*)d_out;

    const size_t qkv_elems = (size_t)NBATCH * NH * SEQ * HD;  // 8.39M
    char* p = (char*)d_ws;
    float* cos_t = (float*)p; p += (size_t)SEQ * 64 * 4;
    float* sin_t = (float*)p; p += (size_t)SEQ * 64 * 4;
    short* qbf   = (short*)p; p += qkv_elems * 2;
    short* kbf   = (short*)p; p += qkv_elems * 2;
    short* vTt   = (short*)p; p += qkv_elems * 2;
    short* Wqkvh = (short*)p; p += (size_t)3 * HID * HID * 2;
    short* Wouth = (short*)p; p += (size_t)HID * HID * 2;
    short* Ahs   = (short*)p; p += qkv_elems * 2;   // bf16(hs); aliased ctx after QKV
    short* ctxb  = Ahs;

    rope_table_kernel<<<(SEQ * 64 + 255) / 256, 256, 0, stream>>>(cos_t, sin_t);

    split_h_kernel<<<(int)(qkv_elems / 4 / 256), 256, 0, stream>>>(
        hs, Ahs, (int)(qkv_elems / 4));
    split_h_kernel<<<(int)((size_t)3 * HID * HID / 4 / 256), 256, 0, stream>>>(
        Wqkv, Wqkvh, (int)((size_t)3 * HID * HID / 4));
    split_h_kernel<<<(int)((size_t)HID * HID / 4 / 256), 256, 0, stream>>>(
        Wout, Wouth, (int)((size_t)HID * HID / 4));

    // QKV: M=4096, N=6144, K=2048 (bf16 MFMA, single chain)
    gemm_bf16_kernel<0><<<dim3(48, 32), 256, 0, stream>>>(
        Ahs, Wqkvh, bqkv, nullptr, qbf, kbf, vTt, cos_t, sin_t);

    // attention
    attn_mfma_kernel<<<dim3(SEQ / 64, NH * NBATCH), 256, 0, stream>>>(
        qbf, kbf, vTt, mask, ctxb);

    // out-proj: M=4096, N=2048, K=2048
    gemm_bf16_kernel<1><<<dim3(16, 32), 256, 0, stream>>>(
        ctxb, Wouth, bout, out, nullptr, nullptr, nullptr, nullptr, nullptr);
}

// Round 8
// 456.480 us; speedup vs baseline: 7.3369x; 1.0515x over previous
//
#include <hip/hip_runtime.h>
#include <math.h>

#define HID    2048
#define NH     16
#define HD     128
#define SEQ    2048
#define NBATCH 2

typedef __attribute__((ext_vector_type(8))) short bf16x8;   // 8 bf16 = 4 VGPRs
typedef __attribute__((ext_vector_type(4))) float f32x4;    // MFMA accumulator

__device__ __forceinline__ short f2bf(float f) {            // fp32 -> bf16 RNE
    union { float f; unsigned u; } x; x.f = f;
    unsigned r = x.u + 0x7fffu + ((x.u >> 16) & 1u);
    return (short)(r >> 16);
}
__device__ __forceinline__ float bf2f(short s) {
    union { unsigned u; float f; } y;
    y.u = ((unsigned)(unsigned short)s) << 16;
    return y.f;
}

// async global->LDS, 16 B per lane; LDS dest = wave-uniform base + lane*16
__device__ __forceinline__ void gl_lds16(const short* g, short* l) {
    __builtin_amdgcn_global_load_lds(
        (const __attribute__((address_space(1))) unsigned int*)g,
        (__attribute__((address_space(3))) unsigned int*)l, 16, 0, 0);
}

// ---------------------------------------------------------------------------
// RoPE tables
// ---------------------------------------------------------------------------
__global__ __launch_bounds__(256) void rope_table_kernel(float* __restrict__ ct,
                                                         float* __restrict__ st) {
    int idx = blockIdx.x * 256 + threadIdx.x;
    if (idx >= SEQ * 64) return;
    int s = idx >> 6;
    int i = idx & 63;
    double inv = pow(10000.0, -(double)i / 64.0);
    float freq = (float)s * (float)inv;
    ct[idx] = cosf(freq);
    st[idx] = sinf(freq);
}

// ---------------------------------------------------------------------------
// fp32 -> bf16 (RNE) cast
// ---------------------------------------------------------------------------
__global__ __launch_bounds__(256) void split_h_kernel(const float* __restrict__ in,
                                                      short* __restrict__ oh, int n4) {
    int i = blockIdx.x * 256 + threadIdx.x;
    if (i >= n4) return;
    float4 v = ((const float4*)in)[i];
    short4 h;
    h.x = f2bf(v.x); h.y = f2bf(v.y); h.z = f2bf(v.z); h.w = f2bf(v.w);
    *(short4*)(oh + 4 * (size_t)i) = h;
}

// ---------------------------------------------------------------------------
// bf16 MFMA GEMM (m97 structure): C = A.B^T + bias, single bf16 chain.
// 128x128 tile, BK=32, 4 waves (2x2 of 64x64), 4x4 16x16x32 MFMAs.
// MODE 0: QKV -> RoPE (shfl pair) -> q (pre-scaled by 1/sqrt(d)) / k bf16
//         [b][h][s][d] + vT [b][h][d][s]
// MODE 1: out-proj -> fp32 C
// ---------------------------------------------------------------------------
#define LDSA 0
#define LDSB 4096

template <int MODE>
__global__ __launch_bounds__(256, 3) void gemm_bf16_kernel(
    const short* __restrict__ Ah, const short* __restrict__ Bh,
    const float* __restrict__ bias, float* __restrict__ C,
    short* __restrict__ qb, short* __restrict__ kbf, short* __restrict__ vTt,
    const float* __restrict__ ct, const float* __restrict__ st) {
    __shared__ short lds[MODE == 0 ? 18432 : 8192];  // staging 16 KB; V-transp 36 KB

    const int t     = threadIdx.x;
    const int w     = t >> 6;
    const int lane  = t & 63;
    const int mfrag = lane & 15;
    const int quad  = lane >> 4;
    const int wm    = (w >> 1) * 64;
    const int wn    = (w & 1) * 64;
    const int m0    = blockIdx.y * 128;
    const int n0    = blockIdx.x * 128;

    const int srow   = lane >> 2;
    const int schunk = (((lane & 3) ^ ((lane >> 3) & 3))) * 8;
    const short* gA0 = Ah + (size_t)(m0 + w * 16 + srow) * HID + schunk;
    const short* gA1 = Ah + (size_t)(m0 + 64 + w * 16 + srow) * HID + schunk;
    const short* gB0 = Bh + (size_t)(n0 + w * 16 + srow) * HID + schunk;
    const short* gB1 = Bh + (size_t)(n0 + 64 + w * 16 + srow) * HID + schunk;
    short* lA0 = &lds[LDSA + (w * 16) * 32];
    short* lA1 = &lds[LDSA + (64 + w * 16) * 32];
    short* lB0 = &lds[LDSB + (w * 16) * 32];
    short* lB1 = &lds[LDSB + (64 + w * 16) * 32];

    const int chA = 8 * (quad ^ ((mfrag >> 1) & 3));  // inverse swizzle

    f32x4 acc[4][4];
#pragma unroll
    for (int i = 0; i < 4; ++i)
#pragma unroll
        for (int j = 0; j < 4; ++j) acc[i][j] = (f32x4){0.f, 0.f, 0.f, 0.f};

    for (int kt = 0; kt < HID; kt += 32) {
        __syncthreads();
        gl_lds16(gA0 + kt, lA0);
        gl_lds16(gA1 + kt, lA1);
        gl_lds16(gB0 + kt, lB0);
        gl_lds16(gB1 + kt, lB1);
        __syncthreads();

        bf16x8 ah[4], bh[4];
#pragma unroll
        for (int mt = 0; mt < 4; ++mt)
            ah[mt] = *(const bf16x8*)&lds[LDSA + (wm + mt * 16 + mfrag) * 32 + chA];
#pragma unroll
        for (int nt = 0; nt < 4; ++nt)
            bh[nt] = *(const bf16x8*)&lds[LDSB + (wn + nt * 16 + mfrag) * 32 + chA];

#pragma unroll
        for (int mt = 0; mt < 4; ++mt)
#pragma unroll
            for (int nt = 0; nt < 4; ++nt)
                acc[mt][nt] = __builtin_amdgcn_mfma_f32_16x16x32_bf16(
                    ah[mt], bh[nt], acc[mt][nt], 0, 0, 0);
    }

    float bcol[4];
#pragma unroll
    for (int nt = 0; nt < 4; ++nt) bcol[nt] = bias[n0 + wn + nt * 16 + mfrag];

    if (MODE == 0) {
        const int which = n0 >> 11;          // 0=q 1=k 2=v
        const int h     = (n0 & 2047) >> 7;
        const int bidx  = m0 >> 11;
        if (which < 2) {
            short* dst = (which == 0) ? qb : kbf;
            const float post = (which == 0) ? 0.08838834764831845f : 1.0f;
#pragma unroll
            for (int mt = 0; mt < 4; ++mt)
#pragma unroll
                for (int r = 0; r < 4; ++r) {
                    int sl = (m0 & 2047) + wm + mt * 16 + 4 * quad + r;
#pragma unroll
                    for (int nt = 0; nt < 4; ++nt) {
                        float x  = acc[mt][nt][r] + bcol[nt];
                        float px = __shfl_xor(x, 1, 64);   // RoPE pair partner
                        int   d  = wn + nt * 16 + mfrag;
                        float c  = ct[sl * 64 + (d >> 1)];
                        float sn = st[sl * 64 + (d >> 1)];
                        float rot = (mfrag & 1) ? fmaf(px, sn, x * c)
                                                : (x * c - px * sn);
                        dst[((size_t)(bidx * NH + h) * SEQ + sl) * HD + d] =
                            f2bf(rot * post);
                    }
                }
        } else {
            // V: per-wave LDS transpose -> vT [b][h][d][s]
            __syncthreads();   // staging reads done; reuse LDS (which is per-block)
            short* tw = &lds[w * 4608];      // 64 x 72 shorts, wave-private
#pragma unroll
            for (int mt = 0; mt < 4; ++mt)
#pragma unroll
                for (int nt = 0; nt < 4; ++nt)
#pragma unroll
                    for (int r = 0; r < 4; ++r)
                        tw[(nt * 16 + mfrag) * 72 + (mt * 16 + 4 * quad + r)] =
                            f2bf(acc[mt][nt][r] + bcol[nt]);
            const size_t vbase = (size_t)(bidx * NH + h) * HD * SEQ;
            const int sbase = (m0 & 2047) + wm;
#pragma unroll
            for (int it = 0; it < 8; ++it) {
                int dl  = it * 8 + (lane >> 3);
                int cch = (lane & 7) ^ (lane >> 3);
                bf16x8 row = *(const bf16x8*)&tw[dl * 72 + cch * 8];
                *(bf16x8*)(vTt + vbase + (size_t)(wn + dl) * SEQ + sbase + cch * 8) = row;
            }
        }
    } else {
#pragma unroll
        for (int mt = 0; mt < 4; ++mt)
#pragma unroll
            for (int r = 0; r < 4; ++r) {
                int m = m0 + wm + mt * 16 + 4 * quad + r;
#pragma unroll
                for (int nt = 0; nt < 4; ++nt)
                    C[(size_t)m * HID + n0 + wn + nt * 16 + mfrag] =
                        acc[mt][nt][r] + bcol[nt];
            }
    }
}

// ---------------------------------------------------------------------------
// MFMA flash attention, 512-thread blocks (8 waves), q-tile 128 (16 rows/wave),
// KV tile 64 staged once per block. XCD-swizzled block id: all 16 q-blocks of
// one (b,h) land on one XCD (K/V L2-resident per XCD). Q pre-scaled.
// LDS: K 16 KB | V 16 KB | P 18 KB = 50 KB -> 2 blocks/CU (grid = exactly 2/CU).
// ---------------------------------------------------------------------------
#define LDSK 0
#define LDSV 8192
#define LDSP 16384

__global__ __launch_bounds__(512, 4) void attn_mfma_kernel(
    const short* __restrict__ qb, const short* __restrict__ kbf,
    const short* __restrict__ vTt, const float* __restrict__ mask,
    short* __restrict__ ctxb) {
    __shared__ __align__(16) short lds[25600];   // K 8192 | V 8192 | P 9216 shorts

    const int t    = threadIdx.x;
    const int w    = t >> 6;            // 0..7
    const int lane = t & 63;
    const int m    = lane & 15;
    const int quad = lane >> 4;

    // XCD swizzle: id&7 = XCD; 4 heads per XCD; 16 q-blocks per head
    const int id  = blockIdx.x;
    const int j   = id >> 3;
    const int bh  = (id & 7) * 4 + (j >> 4);
    const int q0  = (j & 15) * 128;
    const int b   = bh >> 4;
    const int h   = bh & 15;

    const size_t base = (size_t)bh * SEQ * HD;
    const short* kp = kbf + base;        // [s][d]
    const short* vp = vTt + base;        // [d][s]
    const float* mrow = mask + (size_t)b * SEQ;

    // staging addresses (swizzled source granule; LDS dest lane-contiguous)
    // K: 64 rows x 16 granules; wave w covers rows [w*8, w*8+8)
    // V: 128 rows x 8 granules;  wave w covers rows [w*16, w*16+16)
    size_t kOff[2], vOff[2];
    short *ldsK[2], *ldsV[2];
#pragma unroll
    for (int u = 0; u < 2; ++u) {
        int rk = w * 8 + u * 4 + (lane >> 4);
        int ck = (lane & 15) ^ (rk & 7);
        kOff[u] = (size_t)rk * HD + ck * 8;
        ldsK[u] = &lds[LDSK + (w * 8 + u * 4) * 128];
        int rv = w * 16 + u * 8 + (lane >> 3);
        int cv = (lane & 7) ^ (rv & 7);
        vOff[u] = (size_t)rv * SEQ + cv * 8;
        ldsV[u] = &lds[LDSV + (w * 16 + u * 8) * 64];
    }

    // Q fragments (16 rows/wave), direct global, once
    const int srow = q0 + w * 16 + m;
    bf16x8 qh[4];
    {
        const short* qhp = qb + base + (size_t)srow * HD;
#pragma unroll
        for (int c = 0; c < 4; ++c)
            qh[c] = *(const bf16x8*)(qhp + 32 * c + 8 * quad);
    }

    f32x4 O[8];
    float m_i[4], l_i[4];
#pragma unroll
    for (int c = 0; c < 8; ++c) O[c] = (f32x4){0.f, 0.f, 0.f, 0.f};
#pragma unroll
    for (int r = 0; r < 4; ++r) { m_i[r] = -INFINITY; l_i[r] = 0.f; }

    const int sw = m & 7;     // fragment-read inverse swizzle key

    for (int kt = 0; kt < SEQ / 64; ++kt) {
        const int k0 = kt * 64;

        __syncthreads();
#pragma unroll
        for (int u = 0; u < 2; ++u) {
            gl_lds16(kp + (size_t)k0 * HD + kOff[u], ldsK[u]);
            gl_lds16(vp + k0 + vOff[u], ldsV[u]);
        }
        __syncthreads();

        float mk[4];
#pragma unroll
        for (int c2 = 0; c2 < 4; ++c2) mk[c2] = mrow[k0 + 16 * c2 + m];

        // ---- QK^T from LDS (Q pre-scaled) ----
        f32x4 S[4];
#pragma unroll
        for (int c2 = 0; c2 < 4; ++c2) {
            f32x4 acc = (f32x4){0.f, 0.f, 0.f, 0.f};
#pragma unroll
            for (int c = 0; c < 4; ++c) {
                int pk = (4 * c + quad) ^ sw;
                bf16x8 kf = *(const bf16x8*)&lds[LDSK + (16 * c2 + m) * 128 + pk * 8];
                acc = __builtin_amdgcn_mfma_f32_16x16x32_bf16(qh[c], kf, acc, 0, 0, 0);
            }
            S[c2] = acc;
        }

        // ---- online softmax ----
        float alpha[4], p[4][4];
#pragma unroll
        for (int r = 0; r < 4; ++r) {
            float s0 = S[0][r] + mk[0];
            float s1 = S[1][r] + mk[1];
            float s2 = S[2][r] + mk[2];
            float s3 = S[3][r] + mk[3];
            float rm = fmaxf(fmaxf(s0, s1), fmaxf(s2, s3));
#pragma unroll
            for (int off = 1; off < 16; off <<= 1)
                rm = fmaxf(rm, __shfl_xor(rm, off, 64));
            float mn = fmaxf(m_i[r], rm);
            alpha[r] = __expf(m_i[r] - mn);
            p[0][r] = __expf(s0 - mn);
            p[1][r] = __expf(s1 - mn);
            p[2][r] = __expf(s2 - mn);
            p[3][r] = __expf(s3 - mn);
            float ts = (p[0][r] + p[1][r]) + (p[2][r] + p[3][r]);
#pragma unroll
            for (int off = 1; off < 16; off <<= 1)
                ts += __shfl_xor(ts, off, 64);
            l_i[r] = l_i[r] * alpha[r] + ts;
            m_i[r] = mn;
        }

        // ---- P: C-layout -> A-layout via wave-private LDS ----
#pragma unroll
        for (int c2 = 0; c2 < 4; ++c2)
#pragma unroll
            for (int r = 0; r < 4; ++r)
                lds[LDSP + w * 1152 + (4 * quad + r) * 72 + 16 * c2 + m] =
                    f2bf(p[c2][r]);

        // ---- rescale O, then PV from LDS ----
#pragma unroll
        for (int c = 0; c < 8; ++c)
#pragma unroll
            for (int r = 0; r < 4; ++r) O[c][r] *= alpha[r];

#pragma unroll
        for (int cc = 0; cc < 2; ++cc) {
            bf16x8 pf = *(const bf16x8*)&lds[LDSP + w * 1152 + m * 72 +
                                             32 * cc + 8 * quad];
#pragma unroll
            for (int c = 0; c < 8; ++c) {
                int pv = (4 * cc + quad) ^ sw;
                bf16x8 vf = *(const bf16x8*)&lds[LDSV + (16 * c + m) * 64 + pv * 8];
                O[c] = __builtin_amdgcn_mfma_f32_16x16x32_bf16(pf, vf, O[c], 0, 0, 0);
            }
        }
    }

    // ---- epilogue: ctx bf16 [b][s][h*128+d] ----
#pragma unroll
    for (int r = 0; r < 4; ++r) {
        float inv = 1.0f / l_i[r];
        int s = q0 + w * 16 + 4 * quad + r;
        size_t off = ((size_t)(b * SEQ + s)) * HID + h * HD;
#pragma unroll
        for (int c = 0; c < 8; ++c)
            ctxb[off + 16 * c + m] = f2bf(O[c][r] * inv);
    }
}

// ---------------------------------------------------------------------------
extern "C" void kernel_launch(void* const* d_in, const int* in_sizes, int n_in,
                              void* d_out, int out_size, void* d_ws, size_t ws_size,
                              hipStream_t stream) {
    const float* hs   = (const float*)d_in[0];
    const float* mask = (const float*)d_in[1];
    const float* Wqkv = (const float*)d_in[2];
    const float* bqkv = (const float*)d_in[3];
    const float* Wout = (const float*)d_in[4];
    const float* bout = (const float*)d_in[5];
    float* out = (float*)d_out;

    const size_t qkv_elems = (size_t)NBATCH * NH * SEQ * HD;  // 8.39M
    char* p = (char*)d_ws;
    float* cos_t = (float*)p; p += (size_t)SEQ * 64 * 4;
    float* sin_t = (float*)p; p += (size_t)SEQ * 64 * 4;
    short* qbf   = (short*)p; p += qkv_elems * 2;
    short* kbf   = (short*)p; p += qkv_elems * 2;
    short* vTt   = (short*)p; p += qkv_elems * 2;
    short* Wqkvh = (short*)p; p += (size_t)3 * HID * HID * 2;
    short* Wouth = (short*)p; p += (size_t)HID * HID * 2;
    short* Ahs   = (short*)p; p += qkv_elems * 2;   // bf16(hs); aliased ctx after QKV
    short* ctxb  = Ahs;

    rope_table_kernel<<<(SEQ * 64 + 255) / 256, 256, 0, stream>>>(cos_t, sin_t);

    split_h_kernel<<<(int)(qkv_elems / 4 / 256), 256, 0, stream>>>(
        hs, Ahs, (int)(qkv_elems / 4));
    split_h_kernel<<<(int)((size_t)3 * HID * HID / 4 / 256), 256, 0, stream>>>(
        Wqkv, Wqkvh, (int)((size_t)3 * HID * HID / 4));
    split_h_kernel<<<(int)((size_t)HID * HID / 4 / 256), 256, 0, stream>>>(
        Wout, Wouth, (int)((size_t)HID * HID / 4));

    // QKV: M=4096, N=6144, K=2048 (bf16 MFMA, single chain)
    gemm_bf16_kernel<0><<<dim3(48, 32), 256, 0, stream>>>(
        Ahs, Wqkvh, bqkv, nullptr, qbf, kbf, vTt, cos_t, sin_t);

    // attention: 512 XCD-swizzled blocks of 512 threads
    attn_mfma_kernel<<<512, 512, 0, stream>>>(qbf, kbf, vTt, mask, ctxb);

    // out-proj: M=4096, N=2048, K=2048
    gemm_bf16_kernel<1><<<dim3(16, 32), 256, 0, stream>>>(
        ctxb, Wouth, bout, out, nullptr, nullptr, nullptr, nullptr, nullptr);
}